// Round 13
// baseline (2562.096 us; speedup 1.0000x reference)
//
#include <hip/hip_runtime.h>
#include <cstddef>
#include <cstdint>

typedef __attribute__((ext_vector_type(8))) short bf16x8;
typedef __attribute__((ext_vector_type(16))) float f32x16;
typedef __attribute__((ext_vector_type(4))) unsigned short us4;

// ---------------- workspace layout (byte offsets) ----------------
static const size_t B_BIASC = 0;            // 6*160*4 = 3,840
static const size_t B_KTH   = 3840;         // 20*1024*32*2 = 1,310,720
static const size_t B_KTL   = 1314560;      // 1,310,720
static const size_t B_VT    = 2625280;      // 20*128*1024*2 = 5,242,880
static const size_t B_KQH   = 7868160;      // 5*2*1024*32*2 = 655,360
static const size_t B_KQL   = 8523520;      // 655,360
static const size_t B_VQ    = 9178880;      // 5*2*128*1024*2 = 2,621,440
static const size_t B_MEAN  = 11800320;     // 5*512*4 = 10,240
static const size_t B_FSM   = 11810560;     // 5*2*256*1024*2 = 5,242,880 (bf16)
static const size_t B_MU    = 17053440;     // 5*256*4 = 5,120
static const size_t B_VAR   = 17058560;     // 5,120
static const size_t B_WC    = 17063680;     // 5*256*512*2 = 1,310,720
static const size_t B_BIAS2 = 18374400;     // 5,120
static const size_t B_UNION = 18379520;     // 41,943,040 union region
// phase 1: X_all_hi +0 (15,728,640), X_all_lo +15,728,640, wp_hi +31,457,280, wp_lo +35,880,960
// phase 2 (per level): part2 +0 (41,943,040) -> reduce40 -> fsm
// phase 3: finup bf16 +0 (22,347,776) after part2 dead
static const size_t U_XH    = 0;
static const size_t U_XL    = 15728640;
static const size_t U_WPH   = 31457280;
static const size_t U_WPL   = 35880960;
static const size_t U_FPART = 0;
static const size_t B_ML    = 60322560;     // 2*20*2*1024*8 = 655,360 (float2 m,l)
static const size_t WS_BYTES = 60977920;    // ~61.0 MB

// ---------------- bf16 helpers (RNE) ----------------
__device__ inline unsigned short f2bf(float x) {
    unsigned u = __float_as_uint(x);
    return (unsigned short)((u + 0x7fffu + ((u >> 16) & 1u)) >> 16);
}
__device__ inline float bf2f(unsigned short u) {
    return __uint_as_float(((unsigned)u) << 16);
}
__device__ inline void bf16split(float x, unsigned short& hi, unsigned short& lo) {
    unsigned u = __float_as_uint(x);
    unsigned hb = (u + 0x7fffu + ((u >> 16) & 1u)) >> 16;
    hi = (unsigned short)hb;
    float hf = __uint_as_float(hb << 16);
    float r = x - hf;
    unsigned ur = __float_as_uint(r);
    lo = (unsigned short)((ur + 0x7fffu + ((ur >> 16) & 1u)) >> 16);
}
__device__ inline const float* sel5(const float* a, const float* b, const float* c,
                                    const float* d, const float* e, int i) {
    return i == 0 ? a : i == 1 ? b : i == 2 ? c : i == 3 ? d : e;
}

// ---------------- weight pre-transform ----------------
__global__ __launch_bounds__(256) void prep_weights(
    const float* __restrict__ kt_w, const float* __restrict__ kt_b,
    const float* __restrict__ vt_w, const float* __restrict__ vt_b,
    const float* __restrict__ kq_w, const float* __restrict__ kq_b,
    const float* __restrict__ vq_w, const float* __restrict__ vq_b,
    short* __restrict__ wp_hi, short* __restrict__ wp_lo, float* __restrict__ biasc)
{
    const int oc = blockIdx.x;    // 0..159
    const int s  = blockIdx.y;    // 0..5 (0 = stage A, 1+idx = level)
    const int ic = threadIdx.x;   // 0..255
    const bool iskey = oc < 32;
    const int ocl = iskey ? oc : oc - 32;
    const float scale = (iskey && s > 0) ? 1.4426950408889634f : 1.0f;
    const float* w = iskey
        ? (s == 0 ? kt_w : kq_w + (size_t)(s - 1) * 32 * 256 * 9)
        : (s == 0 ? vt_w : vq_w + (size_t)(s - 1) * 128 * 256 * 9);
    const float* wsrc = w + ((size_t)ocl * 256 + ic) * 9;
#pragma unroll
    for (int t = 0; t < 9; ++t) {
        unsigned short h, l; bf16split(wsrc[t] * scale, h, l);
        size_t d = ((size_t)(s * 9 + t) * 160 + oc) * 256 + ic;
        wp_hi[d] = (short)h; wp_lo[d] = (short)l;
    }
    if (ic == 0) {
        const float* bptr = iskey
            ? (s == 0 ? kt_b : kq_b + (s - 1) * 32)
            : (s == 0 ? vt_b : vq_b + (s - 1) * 128);
        biasc[s * 160 + oc] = bptr[ocl] * scale;
    }
}

// ---------------- fp32 [20][256][1024] -> bf16 hi/lo X_all imgs 0..19 ----------------
__global__ __launch_bounds__(256) void transpose_split(
    const float* __restrict__ in,
    unsigned short* __restrict__ oh, unsigned short* __restrict__ ol)
{
    __shared__ float s[16][260];
    const int n = blockIdx.x, ch = blockIdx.y, p0 = blockIdx.z * 256;
    const int tid = threadIdx.x;
#pragma unroll
    for (int i = 0; i < 16; ++i)
        s[i][tid] = in[((size_t)(n * 256 + ch * 16 + i)) * 1024 + p0 + tid];
    __syncthreads();
    union { unsigned short u[16]; bf16x8 v[2]; } h8, l8;
#pragma unroll
    for (int i = 0; i < 16; ++i) bf16split(s[i][tid], h8.u[i], l8.u[i]);
    size_t base = ((size_t)(n * 16 + ch) * 1024 + p0 + tid) * 16;
    *(bf16x8*)&oh[base] = h8.v[0]; *(bf16x8*)&oh[base + 8] = h8.v[1];
    *(bf16x8*)&ol[base] = l8.v[0]; *(bf16x8*)&ol[base + 8] = l8.v[1];
}

// ---------------- batched per (lvl,b,c) spatial mean ----------------
__global__ __launch_bounds__(256) void mean2d_all(
    const float* f0, const float* f1, const float* f2, const float* f3, const float* f4,
    float* __restrict__ mean)
{
    const int lvl = blockIdx.y;
    const float* f = sel5(f0, f1, f2, f3, f4, lvl);
    const int H = 128 >> lvl, HW = H * H;
    const int bc = blockIdx.x;
    const float* src = f + (size_t)bc * HW;
    float s = 0.f;
    for (int i = threadIdx.x; i < HW; i += 256) s += src[i];
#pragma unroll
    for (int off = 32; off; off >>= 1) s += __shfl_xor(s, off);
    __shared__ float red[4];
    if ((threadIdx.x & 63) == 0) red[threadIdx.x >> 6] = s;
    __syncthreads();
    if (threadIdx.x == 0)
        mean[lvl * 512 + bc] = (red[0] + red[1] + red[2] + red[3]) / (float)HW;
}

// ---------------- batched resize (HxH->32x32) + mean-sub -> X_all imgs 20..29 ----------------
__global__ __launch_bounds__(256) void resizeT_all(
    const float* f0, const float* f1, const float* f2, const float* f3, const float* f4,
    const float* __restrict__ mean,
    unsigned short* __restrict__ oh, unsigned short* __restrict__ ol)
{
    __shared__ float s[16][260];
    const int lvl = blockIdx.z >> 2;
    const int p0 = (blockIdx.z & 3) * 256;
    const int b = blockIdx.x, ch = blockIdx.y;
    const float* f = sel5(f0, f1, f2, f3, f4, lvl);
    const int H = 128 >> lvl;
    const int img = 20 + lvl * 2 + b;
    const int tid = threadIdx.x;
    const int p = p0 + tid, y = p >> 5, x = p & 31;
    float fy = (float)y * (float)(H - 1) / 31.0f;
    float fx = (float)x * (float)(H - 1) / 31.0f;
    int y0 = (int)fy; int y1 = min(y0 + 1, H - 1); float wy = fy - (float)y0;
    int x0 = (int)fx; int x1 = min(x0 + 1, H - 1); float wx = fx - (float)x0;
#pragma unroll
    for (int i = 0; i < 16; ++i) {
        int c = ch * 16 + i;
        const float* pf = f + ((size_t)(b * 256 + c)) * H * H;
        float a = pf[y0 * H + x0], bb = pf[y1 * H + x0];
        float cc = pf[y0 * H + x1], d = pf[y1 * H + x1];
        float c0 = a + (bb - a) * wy;
        float c1 = cc + (d - cc) * wy;
        s[i][tid] = c0 + (c1 - c0) * wx - mean[lvl * 512 + b * 256 + c];
    }
    __syncthreads();
    union { unsigned short u[16]; bf16x8 v[2]; } h8, l8;
#pragma unroll
    for (int i = 0; i < 16; ++i) bf16split(s[i][tid], h8.u[i], l8.u[i]);
    size_t base = ((size_t)(img * 16 + ch) * 1024 + p) * 16;
    *(bf16x8*)&oh[base] = h8.v[0]; *(bf16x8*)&oh[base + 8] = h8.v[1];
    *(bf16x8*)&ol[base] = l8.v[0]; *(bf16x8*)&ol[base + 8] = l8.v[1];
}

// ---------------- merged direct MFMA 3x3 conv, XCD-swizzled 1D grid ----------------
__global__ __launch_bounds__(256) void conv3x3_all(
    const unsigned short* __restrict__ xT_h,  // [30][16][1024][16]
    const unsigned short* __restrict__ xT_l,
    const short* __restrict__ wp_hi_all,      // [6][9][160][256]
    const short* __restrict__ wp_lo_all,
    const float* __restrict__ biasc_all,      // [6][160]
    unsigned short* __restrict__ kt_hi, unsigned short* __restrict__ kt_lo,
    unsigned short* __restrict__ vt,
    unsigned short* __restrict__ kq_hi, unsigned short* __restrict__ kq_lo,
    unsigned short* __restrict__ vq)
{
    const int bid = blockIdx.x;
    const int xcd = bid & 7;
    const int j   = bid >> 3;        // 0..319
    const int grp = j % 5;
    const int k   = j / 5;           // 0..63
    const int yp  = k & 15;
    const int imgh = k >> 4;         // 0..3
    const int img = xcd + 8 * imgh;  // 0..31
    if (img >= 30) return;

    __shared__ float s_red[4][2][16][64];     // 32 KB
    const int tid = threadIdx.x;
    const bool iskey = (grp == 0);
    const int set = (img < 20) ? 0 : 1 + ((img - 20) >> 1);
    const int ocb = grp * 32;
    const int wave = tid >> 6, lane = tid & 63, l31 = tid & 31, lh = (tid >> 5) & 1;
    const int y0 = yp * 2;

    f32x16 acc0 = {}, acc1 = {};
    const bf16x8 bz = {};
    const unsigned short* xh = xT_h + (size_t)img * 16 * 16384;
    const unsigned short* xl = xT_l + (size_t)img * 16 * 16384;
    const short* wph = wp_hi_all + (size_t)set * 368640;
    const short* wpl = wp_lo_all + (size_t)set * 368640;
    const float* bset = biasc_all + set * 160;

    for (int cc = 0; cc < 4; ++cc) {
        const int ch = (wave << 2) + cc;
        const unsigned short* xhc = xh + (size_t)ch * 16384 + lh * 8;
        const unsigned short* xlc = xl + (size_t)ch * 16384 + lh * 8;
#pragma unroll
        for (int tg = 0; tg < 3; ++tg) {
            bf16x8 wh[3], wl[3];
#pragma unroll
            for (int tl = 0; tl < 3; ++tl) {
                size_t wi = ((size_t)((tg * 3 + tl) * 160 + ocb + l31)) * 256 + (ch << 4) + lh * 8;
                wh[tl] = *(const bf16x8*)&wph[wi];
                if (iskey) wl[tl] = *(const bf16x8*)&wpl[wi];
            }
#pragma unroll
            for (int nt = 0; nt < 2; ++nt) {
                const int ri = y0 + nt - 1 + tg;
                const bool rok = (ri >= 0 && ri < 32);
#pragma unroll
                for (int tl = 0; tl < 3; ++tl) {
                    const int x = l31 + tl - 1;
                    const bool ok = rok && (x >= 0) && (x < 32);
                    bf16x8 bh = bz, bl = bz;
                    if (ok) {
                        const int p = ri * 32 + x;
                        bh = *(const bf16x8*)&xhc[p * 16];
                        if (iskey) bl = *(const bf16x8*)&xlc[p * 16];
                    }
                    f32x16& a = nt ? acc1 : acc0;
                    a = __builtin_amdgcn_mfma_f32_32x32x16_bf16(wh[tl], bh, a, 0, 0, 0);
                    if (iskey) {
                        a = __builtin_amdgcn_mfma_f32_32x32x16_bf16(wh[tl], bl, a, 0, 0, 0);
                        a = __builtin_amdgcn_mfma_f32_32x32x16_bf16(wl[tl], bh, a, 0, 0, 0);
                    }
                }
            }
        }
    }
#pragma unroll
    for (int r = 0; r < 16; ++r) {
        s_red[wave][0][r][lane] = acc0[r];
        s_red[wave][1][r][lane] = acc1[r];
    }
    __syncthreads();
    float r0[4], r1[4];
#pragma unroll
    for (int jj = 0; jj < 4; ++jj) {
        int r = (wave << 2) + jj;
        r0[jj] = s_red[0][0][r][lane] + s_red[1][0][r][lane] + s_red[2][0][r][lane] + s_red[3][0][r][lane];
        r1[jj] = s_red[0][1][r][lane] + s_red[1][1][r][lane] + s_red[2][1][r][lane] + s_red[3][1][r][lane];
    }
    if (iskey) {
#pragma unroll
        for (int nt = 0; nt < 2; ++nt) {
            const float* rr = nt ? r1 : r0;
            int p = (y0 + nt) * 32 + l31;
            int ocq = 8 * wave + 4 * lh;
            us4 h4, l4;
#pragma unroll
            for (int jj = 0; jj < 4; ++jj) {
                unsigned short h, l;
                bf16split(rr[jj] + bset[ocq + jj], h, l);
                h4[jj] = h; l4[jj] = l;
            }
            if (img < 20) {
                size_t base = ((size_t)img * 1024 + p) * 32;
                *(us4*)&kt_hi[base + ocq] = h4;
                *(us4*)&kt_lo[base + ocq] = l4;
            } else {
                size_t base = ((size_t)(img - 20) * 1024 + p) * 32;
                *(us4*)&kq_hi[base + ocq] = h4;
                *(us4*)&kq_lo[base + ocq] = l4;
            }
        }
    } else {
#pragma unroll
        for (int nt = 0; nt < 2; ++nt) {
            const float* rr = nt ? r1 : r0;
            int p = (y0 + nt) * 32 + l31;
#pragma unroll
            for (int jj = 0; jj < 4; ++jj) {
                int pat = jj + 8 * wave + 4 * lh;
                int vo = (ocb - 32) + pat;
                unsigned short val = f2bf(rr[jj] + bset[32 + vo]);
                if (img < 20) vt[((size_t)img * 128 + vo) * 1024 + p] = val;
                else          vq[((size_t)(img - 20) * 128 + vo) * 1024 + p] = val;
            }
        }
    }
}

// ---------------- flash relation-attention v6: 1-wave blocks (no LDS, no barriers) ----------------
// grid (64 = t32*2+vw, 2 b, 40 = n*2+qg), block 64 = 1 wave.
// Waves were already independent in flash5; 1-wave blocks maximize scheduler freedom.
__global__ __launch_bounds__(64, 4) void flash6(
    const unsigned short* __restrict__ kt_hi, const unsigned short* __restrict__ kt_lo,
    const unsigned short* __restrict__ vt_bf,
    const unsigned short* __restrict__ kq_hi, const unsigned short* __restrict__ kq_lo,
    const unsigned short* __restrict__ vq_bf,
    unsigned short* __restrict__ part2,      // [2 qg][20 n][2 b][256][1024] bf16
    float2* __restrict__ ml_out)             // [2 qg][20 n][2 b][1024] (m, l)
{
    const int tid = threadIdx.x;             // 0..63
    const int l31 = tid & 31, lh = tid >> 5;
    const int t32 = blockIdx.x >> 1;         // 0..31 (32-col t tile)
    const int vw  = blockIdx.x & 1;          // v-half
    const int b   = blockIdx.y;
    const int n   = blockIdx.z >> 1;
    const int qg  = blockIdx.z & 1;
    const int qbase = qg * 512;

    const int trow = t32 * 32 + l31;
    bf16x8 btk_h0, btk_h1, btk_l0, btk_l1;
    {
        size_t g = ((size_t)n * 1024 + trow) * 32 + lh * 8;
        btk_h0 = *(const bf16x8*)&kt_hi[g];
        btk_h1 = *(const bf16x8*)&kt_hi[g + 16];
        btk_l0 = *(const bf16x8*)&kt_lo[g];
        btk_l1 = *(const bf16x8*)&kt_lo[g + 16];
    }

    const unsigned short* vbase = (vw == 0)
        ? (vq_bf + (size_t)b * 131072)
        : (vt_bf + (size_t)n * 131072);
    const unsigned short* vrow[4];
#pragma unroll
    for (int vs = 0; vs < 4; ++vs)
        vrow[vs] = vbase + ((size_t)(vs * 32 + l31)) * 1024 + lh * 8;

    const unsigned short* kqh = kq_hi + (size_t)b * 1024 * 32;
    const unsigned short* kql = kq_lo + (size_t)b * 1024 * 32;

    bf16x8 nva[4][2];
#pragma unroll
    for (int vs = 0; vs < 4; ++vs) {
        nva[vs][0] = *(const bf16x8*)&vrow[vs][qbase];
        nva[vs][1] = *(const bf16x8*)&vrow[vs][qbase + 16];
    }
    bf16x8 nah0 = *(const bf16x8*)&kqh[(size_t)(qbase + l31) * 32 + lh * 8];
    bf16x8 nah1 = *(const bf16x8*)&kqh[(size_t)(qbase + l31) * 32 + 16 + lh * 8];
    bf16x8 nal0 = *(const bf16x8*)&kql[(size_t)(qbase + l31) * 32 + lh * 8];
    bf16x8 nal1 = *(const bf16x8*)&kql[(size_t)(qbase + l31) * 32 + 16 + lh * 8];

    f32x16 acc0 = {}, acc1 = {}, acc2 = {}, acc3 = {};
    float m = -3.0e38f, lsum = 0.f;

    for (int q0 = qbase; q0 < qbase + 512; q0 += 32) {
        bf16x8 va[4][2];
#pragma unroll
        for (int vs = 0; vs < 4; ++vs) { va[vs][0] = nva[vs][0]; va[vs][1] = nva[vs][1]; }
        bf16x8 ah0 = nah0, ah1 = nah1, al0 = nal0, al1 = nal1;

        if (q0 + 32 < qbase + 512) {   // issue next-step loads (overlap with compute)
            const int qn = q0 + 32;
#pragma unroll
            for (int vs = 0; vs < 4; ++vs) {
                nva[vs][0] = *(const bf16x8*)&vrow[vs][qn];
                nva[vs][1] = *(const bf16x8*)&vrow[vs][qn + 16];
            }
            size_t kb = (size_t)(qn + l31) * 32 + lh * 8;
            nah0 = *(const bf16x8*)&kqh[kb];
            nah1 = *(const bf16x8*)&kqh[kb + 16];
            nal0 = *(const bf16x8*)&kql[kb];
            nal1 = *(const bf16x8*)&kql[kb + 16];
        }

        f32x16 s = {};
        __builtin_amdgcn_s_setprio(1);
        s = __builtin_amdgcn_mfma_f32_32x32x16_bf16(ah0, btk_h0, s, 0, 0, 0);
        s = __builtin_amdgcn_mfma_f32_32x32x16_bf16(ah0, btk_l0, s, 0, 0, 0);
        s = __builtin_amdgcn_mfma_f32_32x32x16_bf16(al0, btk_h0, s, 0, 0, 0);
        s = __builtin_amdgcn_mfma_f32_32x32x16_bf16(ah1, btk_h1, s, 0, 0, 0);
        s = __builtin_amdgcn_mfma_f32_32x32x16_bf16(ah1, btk_l1, s, 0, 0, 0);
        s = __builtin_amdgcn_mfma_f32_32x32x16_bf16(al1, btk_h1, s, 0, 0, 0);
        __builtin_amdgcn_s_setprio(0);

        float pmax = s[0];
#pragma unroll
        for (int r = 1; r < 16; ++r) pmax = fmaxf(pmax, s[r]);
        pmax = fmaxf(pmax, __shfl_xor(pmax, 32));
        if (!__all(pmax <= m + 11.5417f)) {   // defer-max, THR = 8 nats in log2
            float mnew = fmaxf(m, pmax);
            float sc = __builtin_amdgcn_exp2f(m - mnew);
            m = mnew; lsum *= sc;
            acc0 *= sc; acc1 *= sc; acc2 *= sc; acc3 *= sc;
        }
        float pv[16]; float ps = 0.f;
#pragma unroll
        for (int r = 0; r < 16; ++r) { pv[r] = __builtin_amdgcn_exp2f(s[r] - m); ps += pv[r]; }
        lsum += ps;

        unsigned a0, a1, a2, a3, c0, c1, c2, c3;
        asm("v_cvt_pk_bf16_f32 %0, %1, %2" : "=v"(a0) : "v"(pv[0]),  "v"(pv[1]));
        asm("v_cvt_pk_bf16_f32 %0, %1, %2" : "=v"(a1) : "v"(pv[2]),  "v"(pv[3]));
        asm("v_cvt_pk_bf16_f32 %0, %1, %2" : "=v"(a2) : "v"(pv[4]),  "v"(pv[5]));
        asm("v_cvt_pk_bf16_f32 %0, %1, %2" : "=v"(a3) : "v"(pv[6]),  "v"(pv[7]));
        asm("v_cvt_pk_bf16_f32 %0, %1, %2" : "=v"(c0) : "v"(pv[8]),  "v"(pv[9]));
        asm("v_cvt_pk_bf16_f32 %0, %1, %2" : "=v"(c1) : "v"(pv[10]), "v"(pv[11]));
        asm("v_cvt_pk_bf16_f32 %0, %1, %2" : "=v"(c2) : "v"(pv[12]), "v"(pv[13]));
        asm("v_cvt_pk_bf16_f32 %0, %1, %2" : "=v"(c3) : "v"(pv[14]), "v"(pv[15]));
        asm("v_permlane32_swap_b32 %0, %1" : "+v"(a0), "+v"(a2));
        asm("v_permlane32_swap_b32 %0, %1" : "+v"(a1), "+v"(a3));
        asm("v_permlane32_swap_b32 %0, %1" : "+v"(c0), "+v"(c2));
        asm("v_permlane32_swap_b32 %0, %1" : "+v"(c1), "+v"(c3));
        union { unsigned u[4]; bf16x8 v; } f0, f1;
        f0.u[0] = a0; f0.u[1] = a1; f0.u[2] = a2; f0.u[3] = a3;
        f1.u[0] = c0; f1.u[1] = c1; f1.u[2] = c2; f1.u[3] = c3;

        __builtin_amdgcn_s_setprio(1);
#pragma unroll
        for (int vs = 0; vs < 4; ++vs) {
            f32x16& a = (vs == 0) ? acc0 : (vs == 1) ? acc1 : (vs == 2) ? acc2 : acc3;
            a = __builtin_amdgcn_mfma_f32_32x32x16_bf16(va[vs][0], f0.v, a, 0, 0, 0);
            a = __builtin_amdgcn_mfma_f32_32x32x16_bf16(va[vs][1], f1.v, a, 0, 0, 0);
        }
        __builtin_amdgcn_s_setprio(0);
    }

    float lt = lsum + __shfl_xor(lsum, 32);
    float linv = 1.f / lt;
    const size_t slab = (size_t)((qg * 20 + n) * 2 + b);
    unsigned short* outp = part2 + slab * 262144;
#pragma unroll
    for (int vs = 0; vs < 4; ++vs) {
        const f32x16& a = (vs == 0) ? acc0 : (vs == 1) ? acc1 : (vs == 2) ? acc2 : acc3;
#pragma unroll
        for (int r = 0; r < 16; ++r) {
            int v = vw * 128 + vs * 32 + (r & 3) + 8 * (r >> 2) + 4 * lh;
            outp[(size_t)v * 1024 + trow] = f2bf(a[r] * linv);
        }
    }
    if (vw == 0 && lh == 0)   // one writer per t-column
        ml_out[slab * 1024 + trow] = make_float2(m, lt);
}

// ---------------- merge 2 q-groups x 20 n-slabs -> bf16 fsm slice ----------------
__global__ __launch_bounds__(256) void reduce40_merge(
    const unsigned short* __restrict__ part,  // [2][20][2][256][1024]
    const float2* __restrict__ ml,            // [2][20][2][1024]
    unsigned short* __restrict__ out)         // [2][256][1024]
{
    size_t i = (size_t)blockIdx.x * 256 + threadIdx.x;   // 0..524287
    const int t = (int)(i & 1023);
    const int b = (int)(i >> 18);
    const int vt_off = (int)(i & 262143);                 // v*1024 + t
    float s = 0.f;
#pragma unroll
    for (int n = 0; n < 20; ++n) {
        float2 ml0 = ml[(size_t)((0 * 20 + n) * 2 + b) * 1024 + t];
        float2 ml1 = ml[(size_t)((20 + n) * 2 + b) * 1024 + t];
        float M = fmaxf(ml0.x, ml1.x);
        float w0 = ml0.y * __builtin_amdgcn_exp2f(ml0.x - M);
        float w1 = ml1.y * __builtin_amdgcn_exp2f(ml1.x - M);
        float inv = 1.f / (w0 + w1);
        float v0 = bf2f(part[(size_t)((0 * 20 + n) * 2 + b) * 262144 + vt_off]);
        float v1 = bf2f(part[(size_t)((20 + n) * 2 + b) * 262144 + vt_off]);
        s += (v0 * w0 + v1 * w1) * inv;
    }
    out[i] = f2bf(s);
}

// ---------------- bilinear upsample fsm (bf16) -> finup (bf16), all levels, coalesced ----------------
// grid (8192, 5); thread does 4 consecutive x positions (H % 4 == 0)
__global__ __launch_bounds__(256) void upsample_all(
    const unsigned short* __restrict__ fsm, unsigned short* __restrict__ finup)
{
    static const size_t CUMF[5] = {0, 8388608, 10485760, 11010048, 11141120};
    const int lvl = blockIdx.y;
    const int lg = 7 - lvl, H = 128 >> lvl, HW = H * H;
    int idx = blockIdx.x * 256 + threadIdx.x;          // quad index
    if (idx >= (2 * 256 * HW) >> 2) return;
    const int p4 = (idx << 2) & (HW - 1);
    const int bc = (idx << 2) >> (2 * lg);             // 0..511 (b*256+c)
    const int y = p4 >> lg, x = p4 & (H - 1);
    const float sc = 31.f / (float)(H - 1);
    float fy = (float)y * sc;
    int y0 = (int)fy; int y1 = min(y0 + 1, 31); float wy = fy - (float)y0;
    const unsigned short* src = fsm + ((size_t)(lvl * 512 + bc)) * 1024;
    us4 o;
#pragma unroll
    for (int j = 0; j < 4; ++j) {
        float fx = (float)(x + j) * sc;
        int x0 = (int)fx; int x1 = min(x0 + 1, 31); float wx = fx - (float)x0;
        float a = bf2f(src[y0 * 32 + x0]), bb = bf2f(src[y1 * 32 + x0]);
        float cc = bf2f(src[y0 * 32 + x1]), d = bf2f(src[y1 * 32 + x1]);
        float c0 = a + (bb - a) * wy;
        float c1 = cc + (d - cc) * wy;
        o[j] = f2bf(c0 + (c1 - c0) * wx);
    }
    *(us4*)&finup[CUMF[lvl] + (size_t)bc * HW + p4] = o;
}

// ---------------- BN stats with fused bilinear upsample (32x32 -> HxH), all levels ----------------
__global__ __launch_bounds__(256) void bnstats2_all(
    const unsigned short* __restrict__ fsm, float* __restrict__ mu, float* __restrict__ var)
{
    const int c = blockIdx.x, lvl = blockIdx.y;
    const int lg = 7 - lvl, H = 128 >> lvl, HW = H * H;
    const float sc = 31.f / (float)(H - 1);
    float s = 0.f, s2 = 0.f;
    for (int u = threadIdx.x; u < 2 * HW; u += 256) {
        int b = (u >= HW) ? 1 : 0;
        int p = u - b * HW;
        int y = p >> lg, x = p & (H - 1);
        float fy = (float)y * sc, fx = (float)x * sc;
        int y0 = (int)fy, x0 = (int)fx;
        int y1 = min(y0 + 1, 31), x1 = min(x0 + 1, 31);
        float wy = fy - (float)y0, wx = fx - (float)x0;
        const unsigned short* src = fsm + ((size_t)(lvl * 2 + b) * 256 + c) * 1024;
        float a = bf2f(src[y0 * 32 + x0]), bb = bf2f(src[y1 * 32 + x0]);
        float cc = bf2f(src[y0 * 32 + x1]), d = bf2f(src[y1 * 32 + x1]);
        float c0 = a + (bb - a) * wy;
        float c1 = cc + (d - cc) * wy;
        float v = c0 + (c1 - c0) * wx;
        s += v; s2 += v * v;
    }
#pragma unroll
    for (int off = 32; off; off >>= 1) {
        s  += __shfl_xor(s, off);
        s2 += __shfl_xor(s2, off);
    }
    __shared__ float r1[4], r2[4];
    if ((threadIdx.x & 63) == 0) { r1[threadIdx.x >> 6] = s; r2[threadIdx.x >> 6] = s2; }
    __syncthreads();
    if (threadIdx.x == 0) {
        float cnt = 2.f * (float)HW;
        float mm = (r1[0] + r1[1] + r1[2] + r1[3]) / cnt;
        float qq = (r2[0] + r2[1] + r2[2] + r2[3]) / cnt;
        mu[lvl * 256 + c] = mm; var[lvl * 256 + c] = qq - mm * mm;
    }
}

// ---------------- fold BN into comb weights, all levels ----------------
__global__ __launch_bounds__(256) void prep_comb_all(
    const float* __restrict__ comb_w, const float* __restrict__ comb_b,
    const float* __restrict__ gamma, const float* __restrict__ beta,
    const float* __restrict__ mu, const float* __restrict__ var,
    short* __restrict__ wc, float* __restrict__ bias2)
{
    const int oc = blockIdx.x, lvl = blockIdx.y;
    const int ic = threadIdx.x;
    float a  = gamma[lvl * 256 + ic] * rsqrtf(var[lvl * 256 + ic] + 1e-5f);
    float bb = beta[lvl * 256 + ic] - mu[lvl * 256 + ic] * a;
    float w1 = comb_w[(size_t)oc * 512 + ic];
    float w2 = comb_w[(size_t)oc * 512 + 256 + ic];
    short* wcl = wc + (size_t)lvl * 131072;
    wcl[(size_t)oc * 512 + ic]       = (short)f2bf(w1);
    wcl[(size_t)oc * 512 + 256 + ic] = (short)f2bf(w2 * a);
    float s = w2 * bb;
#pragma unroll
    for (int off = 32; off; off >>= 1) s += __shfl_xor(s, off);
    __shared__ float red[4];
    if ((threadIdx.x & 63) == 0) red[threadIdx.x >> 6] = s;
    __syncthreads();
    if (threadIdx.x == 0)
        bias2[lvl * 256 + oc] = comb_b[oc] + red[0] + red[1] + red[2] + red[3];
}

// ---------------- comb 1x1 conv v2: 64-col tiles, finup bf16 X, all levels ----------------
// grid (341, 2): x<256 L0, <320 L1, <336 L2, <340 L3, else L4
__global__ __launch_bounds__(256, 1) void comb_all(
    const float* f0, const float* f1, const float* f2, const float* f3, const float* f4,
    const unsigned short* __restrict__ finup,  // packed per-level [2][256][HW] bf16
    const short* __restrict__ wc_all,          // [5][256][512] bf16
    const float* __restrict__ bias2_all,       // [5][256]
    float* __restrict__ out)
{
    __shared__ short s_wc[256 * 40];   // 20 KB
    __shared__ short s_xc[64 * 40];    // 5 KB
    static const size_t CUM[5] = {0, 8388608, 10485760, 11010048, 11141120};
    const int bx = blockIdx.x;
    int lvl, x0;
    if      (bx < 256) { lvl = 0; x0 = bx; }
    else if (bx < 320) { lvl = 1; x0 = bx - 256; }
    else if (bx < 336) { lvl = 2; x0 = bx - 320; }
    else if (bx < 340) { lvl = 3; x0 = bx - 336; }
    else               { lvl = 4; x0 = 0; }
    const int H = 128 >> lvl, HW = H * H;
    const float* f = sel5(f0, f1, f2, f3, f4, lvl);
    const unsigned short* fup = finup + CUM[lvl];
    const short* wc = wc_all + (size_t)lvl * 131072;
    const float* bias2 = bias2_all + lvl * 256;
    float* outl = out + CUM[lvl];

    const int tid = threadIdx.x;
    const int p0 = x0 * 64;
    const int b  = blockIdx.y;
    const int wv = tid >> 6, l31 = tid & 31, lh = (tid >> 5) & 1;

    f32x16 acc[2][2];
#pragma unroll
    for (int i = 0; i < 2; ++i)
#pragma unroll
        for (int j = 0; j < 2; ++j)
#pragma unroll
            for (int r = 0; r < 16; ++r) acc[i][j][r] = 0.f;

    for (int k0 = 0; k0 < 512; k0 += 32) {
        __syncthreads();
        for (int u = tid; u < 512; u += 256) {          // W: 256 rows x 32 k
            int r = u >> 1, h = u & 1;
            *(bf16x8*)&s_wc[r * 40 + h * 16 + 0] = *(const bf16x8*)&wc[(size_t)r * 512 + k0 + h * 16];
            *(bf16x8*)&s_wc[r * 40 + h * 16 + 8] = *(const bf16x8*)&wc[(size_t)r * 512 + k0 + h * 16 + 8];
        }
        for (int u = tid; u < 512; u += 256) {          // X: 32 k x 64 p -> [p][k]
            int kr = u >> 4, n4 = (u & 15) * 4;
            int ck = k0 + kr;
            int p = p0 + n4;
            if (ck < 256) {
                float4 v4 = *(const float4*)&f[((size_t)(b * 256 + ck)) * HW + p];
                s_xc[(n4 + 0) * 40 + kr] = (short)f2bf(v4.x);
                s_xc[(n4 + 1) * 40 + kr] = (short)f2bf(v4.y);
                s_xc[(n4 + 2) * 40 + kr] = (short)f2bf(v4.z);
                s_xc[(n4 + 3) * 40 + kr] = (short)f2bf(v4.w);
            } else {
                us4 v4 = *(const us4*)&fup[((size_t)(b * 256 + ck - 256)) * HW + p];
                s_xc[(n4 + 0) * 40 + kr] = (short)v4[0];
                s_xc[(n4 + 1) * 40 + kr] = (short)v4[1];
                s_xc[(n4 + 2) * 40 + kr] = (short)v4[2];
                s_xc[(n4 + 3) * 40 + kr] = (short)v4[3];
            }
        }
        __syncthreads();
#pragma unroll
        for (int ks = 0; ks < 2; ++ks) {
            bf16x8 a[2], bx2[2];
#pragma unroll
            for (int mi = 0; mi < 2; ++mi)
                a[mi] = *(const bf16x8*)&s_wc[(wv * 64 + mi * 32 + l31) * 40 + ks * 16 + lh * 8];
#pragma unroll
            for (int ni = 0; ni < 2; ++ni)
                bx2[ni] = *(const bf16x8*)&s_xc[(ni * 32 + l31) * 40 + ks * 16 + lh * 8];
#pragma unroll
            for (int mi = 0; mi < 2; ++mi)
#pragma unroll
                for (int ni = 0; ni < 2; ++ni)
                    acc[mi][ni] = __builtin_amdgcn_mfma_f32_32x32x16_bf16(a[mi], bx2[ni], acc[mi][ni], 0, 0, 0);
        }
    }
#pragma unroll
    for (int mi = 0; mi < 2; ++mi) {
#pragma unroll
        for (int ni = 0; ni < 2; ++ni) {
            int p = p0 + ni * 32 + l31;
#pragma unroll
            for (int r = 0; r < 16; ++r) {
                int oc = wv * 64 + mi * 32 + (r & 3) + 8 * (r >> 2) + 4 * lh;
                outl[((size_t)(b * 256 + oc)) * HW + p] = acc[mi][ni][r] + bias2[oc];
            }
        }
    }
}

// ---------------- host orchestration ----------------
extern "C" void kernel_launch(void* const* d_in, const int* in_sizes, int n_in,
                              void* d_out, int out_size, void* d_ws, size_t ws_size,
                              hipStream_t stream) {
    if (ws_size < WS_BYTES) return;

    const float* feats[5];
    for (int i = 0; i < 5; ++i) feats[i] = (const float*)d_in[i];
    const float* attn     = (const float*)d_in[5];
    const float* key_t_w  = (const float*)d_in[6];
    const float* key_t_b  = (const float*)d_in[7];
    const float* val_t_w  = (const float*)d_in[8];
    const float* val_t_b  = (const float*)d_in[9];
    const float* key_q_w  = (const float*)d_in[10];
    const float* key_q_b  = (const float*)d_in[11];
    const float* val_q_w  = (const float*)d_in[12];
    const float* val_q_b  = (const float*)d_in[13];
    const float* bn_gamma = (const float*)d_in[14];
    const float* bn_beta  = (const float*)d_in[15];
    const float* comb_w   = (const float*)d_in[16];
    const float* comb_b   = (const float*)d_in[17];

    char* ws = (char*)d_ws;
    float* biasc = (float*)(ws + B_BIASC);
    unsigned short* kt_hi = (unsigned short*)(ws + B_KTH);
    unsigned short* kt_lo = (unsigned short*)(ws + B_KTL);
    unsigned short* vt    = (unsigned short*)(ws + B_VT);
    unsigned short* kq_hi = (unsigned short*)(ws + B_KQH);
    unsigned short* kq_lo = (unsigned short*)(ws + B_KQL);
    unsigned short* vq    = (unsigned short*)(ws + B_VQ);
    float* mean_f = (float*)(ws + B_MEAN);
    unsigned short* fsm = (unsigned short*)(ws + B_FSM);
    float* mu     = (float*)(ws + B_MU);
    float* var    = (float*)(ws + B_VAR);
    short* wc_bf  = (short*)(ws + B_WC);
    float* bias2  = (float*)(ws + B_BIAS2);
    unsigned short* X_h = (unsigned short*)(ws + B_UNION + U_XH);
    unsigned short* X_l = (unsigned short*)(ws + B_UNION + U_XL);
    short* wp_hi = (short*)(ws + B_UNION + U_WPH);
    short* wp_lo = (short*)(ws + B_UNION + U_WPL);
    unsigned short* part2 = (unsigned short*)(ws + B_UNION + U_FPART);
    float2* ml_arr = (float2*)(ws + B_ML);
    unsigned short* finup = (unsigned short*)(ws + B_UNION);  // after part2 dead

    prep_weights<<<dim3(160, 6), 256, 0, stream>>>(
        key_t_w, key_t_b, val_t_w, val_t_b, key_q_w, key_q_b, val_q_w, val_q_b,
        wp_hi, wp_lo, biasc);

    transpose_split<<<dim3(20, 16, 4), 256, 0, stream>>>(attn, X_h, X_l);

    mean2d_all<<<dim3(512, 5), 256, 0, stream>>>(
        feats[0], feats[1], feats[2], feats[3], feats[4], mean_f);

    resizeT_all<<<dim3(2, 16, 20), 256, 0, stream>>>(
        feats[0], feats[1], feats[2], feats[3], feats[4], mean_f, X_h, X_l);

    conv3x3_all<<<2560, 256, 0, stream>>>(
        X_h, X_l, wp_hi, wp_lo, biasc, kt_hi, kt_lo, vt, kq_hi, kq_lo, vq);

    for (int idx = 0; idx < 5; ++idx) {
        flash6<<<dim3(64, 2, 40), 64, 0, stream>>>(
            kt_hi, kt_lo, vt,
            kq_hi + (size_t)idx * 2 * 32768,
            kq_lo + (size_t)idx * 2 * 32768,
            vq + (size_t)idx * 2 * 131072,
            part2, ml_arr);

        reduce40_merge<<<2048, 256, 0, stream>>>(part2, ml_arr, fsm + (size_t)idx * 524288);
    }

    upsample_all<<<dim3(8192, 5), 256, 0, stream>>>(fsm, finup);

    bnstats2_all<<<dim3(256, 5), 256, 0, stream>>>(fsm, mu, var);

    prep_comb_all<<<dim3(256, 5), 256, 0, stream>>>(
        comb_w, comb_b, bn_gamma, bn_beta, mu, var, wc_bf, bias2);

    comb_all<<<dim3(341, 2), 256, 0, stream>>>(
        feats[0], feats[1], feats[2], feats[3], feats[4],
        finup, wc_bf, bias2, (float*)d_out);
}

// Round 14
// 805.504 us; speedup vs baseline: 3.1807x; 3.1807x over previous
//
#include <hip/hip_runtime.h>
#include <cstddef>
#include <cstdint>

typedef __attribute__((ext_vector_type(8))) short bf16x8;
typedef __attribute__((ext_vector_type(16))) float f32x16;
typedef __attribute__((ext_vector_type(4))) unsigned short us4;

// ---------------- workspace layout (byte offsets) ----------------
static const size_t B_BIASC = 0;            // 6*160*4 = 3,840
static const size_t B_KTH   = 3840;         // 20*1024*32*2 = 1,310,720
static const size_t B_KTL   = 1314560;      // 1,310,720
static const size_t B_VT    = 2625280;      // 20*128*1024*2 = 5,242,880
static const size_t B_KQH   = 7868160;      // 5*2*1024*32*2 = 655,360
static const size_t B_KQL   = 8523520;      // 655,360
static const size_t B_VQ    = 9178880;      // 5*2*128*1024*2 = 2,621,440
static const size_t B_MEAN  = 11800320;     // 5*512*4 = 10,240
static const size_t B_FSM   = 11810560;     // 5*2*256*1024*2 = 5,242,880 (bf16)
static const size_t B_MU    = 17053440;     // 5*256*4 = 5,120
static const size_t B_VAR   = 17058560;     // 5,120
static const size_t B_WC    = 17063680;     // 5*256*512*2 = 1,310,720
static const size_t B_BIAS2 = 18374400;     // 5,120
static const size_t B_UNION = 18379520;     // 41,943,040 union region
// phase 1: X_all_hi +0 (15,728,640), X_all_lo +15,728,640, wp_hi +31,457,280, wp_lo +35,880,960
// phase 2 (per level): part2 +0 (41,943,040) -> reduce40 -> fsm
// phase 3: finup bf16 +0 (22,347,776) after part2 dead
static const size_t U_XH    = 0;
static const size_t U_XL    = 15728640;
static const size_t U_WPH   = 31457280;
static const size_t U_WPL   = 35880960;
static const size_t U_FPART = 0;
static const size_t B_ML    = 60322560;     // 2*20*2*1024*8 = 655,360 (float2 m,l)
static const size_t WS_BYTES = 60977920;    // ~61.0 MB

// ---------------- bf16 helpers (RNE) ----------------
__device__ inline unsigned short f2bf(float x) {
    unsigned u = __float_as_uint(x);
    return (unsigned short)((u + 0x7fffu + ((u >> 16) & 1u)) >> 16);
}
__device__ inline float bf2f(unsigned short u) {
    return __uint_as_float(((unsigned)u) << 16);
}
__device__ inline void bf16split(float x, unsigned short& hi, unsigned short& lo) {
    unsigned u = __float_as_uint(x);
    unsigned hb = (u + 0x7fffu + ((u >> 16) & 1u)) >> 16;
    hi = (unsigned short)hb;
    float hf = __uint_as_float(hb << 16);
    float r = x - hf;
    unsigned ur = __float_as_uint(r);
    lo = (unsigned short)((ur + 0x7fffu + ((ur >> 16) & 1u)) >> 16);
}
__device__ inline const float* sel5(const float* a, const float* b, const float* c,
                                    const float* d, const float* e, int i) {
    return i == 0 ? a : i == 1 ? b : i == 2 ? c : i == 3 ? d : e;
}

// ---------------- weight pre-transform ----------------
__global__ __launch_bounds__(256) void prep_weights(
    const float* __restrict__ kt_w, const float* __restrict__ kt_b,
    const float* __restrict__ vt_w, const float* __restrict__ vt_b,
    const float* __restrict__ kq_w, const float* __restrict__ kq_b,
    const float* __restrict__ vq_w, const float* __restrict__ vq_b,
    short* __restrict__ wp_hi, short* __restrict__ wp_lo, float* __restrict__ biasc)
{
    const int oc = blockIdx.x;    // 0..159
    const int s  = blockIdx.y;    // 0..5 (0 = stage A, 1+idx = level)
    const int ic = threadIdx.x;   // 0..255
    const bool iskey = oc < 32;
    const int ocl = iskey ? oc : oc - 32;
    const float scale = (iskey && s > 0) ? 1.4426950408889634f : 1.0f;
    const float* w = iskey
        ? (s == 0 ? kt_w : kq_w + (size_t)(s - 1) * 32 * 256 * 9)
        : (s == 0 ? vt_w : vq_w + (size_t)(s - 1) * 128 * 256 * 9);
    const float* wsrc = w + ((size_t)ocl * 256 + ic) * 9;
#pragma unroll
    for (int t = 0; t < 9; ++t) {
        unsigned short h, l; bf16split(wsrc[t] * scale, h, l);
        size_t d = ((size_t)(s * 9 + t) * 160 + oc) * 256 + ic;
        wp_hi[d] = (short)h; wp_lo[d] = (short)l;
    }
    if (ic == 0) {
        const float* bptr = iskey
            ? (s == 0 ? kt_b : kq_b + (s - 1) * 32)
            : (s == 0 ? vt_b : vq_b + (s - 1) * 128);
        biasc[s * 160 + oc] = bptr[ocl] * scale;
    }
}

// ---------------- fp32 [20][256][1024] -> bf16 hi/lo X_all imgs 0..19 ----------------
__global__ __launch_bounds__(256) void transpose_split(
    const float* __restrict__ in,
    unsigned short* __restrict__ oh, unsigned short* __restrict__ ol)
{
    __shared__ float s[16][260];
    const int n = blockIdx.x, ch = blockIdx.y, p0 = blockIdx.z * 256;
    const int tid = threadIdx.x;
#pragma unroll
    for (int i = 0; i < 16; ++i)
        s[i][tid] = in[((size_t)(n * 256 + ch * 16 + i)) * 1024 + p0 + tid];
    __syncthreads();
    union { unsigned short u[16]; bf16x8 v[2]; } h8, l8;
#pragma unroll
    for (int i = 0; i < 16; ++i) bf16split(s[i][tid], h8.u[i], l8.u[i]);
    size_t base = ((size_t)(n * 16 + ch) * 1024 + p0 + tid) * 16;
    *(bf16x8*)&oh[base] = h8.v[0]; *(bf16x8*)&oh[base + 8] = h8.v[1];
    *(bf16x8*)&ol[base] = l8.v[0]; *(bf16x8*)&ol[base + 8] = l8.v[1];
}

// ---------------- batched per (lvl,b,c) spatial mean ----------------
__global__ __launch_bounds__(256) void mean2d_all(
    const float* f0, const float* f1, const float* f2, const float* f3, const float* f4,
    float* __restrict__ mean)
{
    const int lvl = blockIdx.y;
    const float* f = sel5(f0, f1, f2, f3, f4, lvl);
    const int H = 128 >> lvl, HW = H * H;
    const int bc = blockIdx.x;
    const float* src = f + (size_t)bc * HW;
    float s = 0.f;
    for (int i = threadIdx.x; i < HW; i += 256) s += src[i];
#pragma unroll
    for (int off = 32; off; off >>= 1) s += __shfl_xor(s, off);
    __shared__ float red[4];
    if ((threadIdx.x & 63) == 0) red[threadIdx.x >> 6] = s;
    __syncthreads();
    if (threadIdx.x == 0)
        mean[lvl * 512 + bc] = (red[0] + red[1] + red[2] + red[3]) / (float)HW;
}

// ---------------- batched resize (HxH->32x32) + mean-sub -> X_all imgs 20..29 ----------------
__global__ __launch_bounds__(256) void resizeT_all(
    const float* f0, const float* f1, const float* f2, const float* f3, const float* f4,
    const float* __restrict__ mean,
    unsigned short* __restrict__ oh, unsigned short* __restrict__ ol)
{
    __shared__ float s[16][260];
    const int lvl = blockIdx.z >> 2;
    const int p0 = (blockIdx.z & 3) * 256;
    const int b = blockIdx.x, ch = blockIdx.y;
    const float* f = sel5(f0, f1, f2, f3, f4, lvl);
    const int H = 128 >> lvl;
    const int img = 20 + lvl * 2 + b;
    const int tid = threadIdx.x;
    const int p = p0 + tid, y = p >> 5, x = p & 31;
    float fy = (float)y * (float)(H - 1) / 31.0f;
    float fx = (float)x * (float)(H - 1) / 31.0f;
    int y0 = (int)fy; int y1 = min(y0 + 1, H - 1); float wy = fy - (float)y0;
    int x0 = (int)fx; int x1 = min(x0 + 1, H - 1); float wx = fx - (float)x0;
#pragma unroll
    for (int i = 0; i < 16; ++i) {
        int c = ch * 16 + i;
        const float* pf = f + ((size_t)(b * 256 + c)) * H * H;
        float a = pf[y0 * H + x0], bb = pf[y1 * H + x0];
        float cc = pf[y0 * H + x1], d = pf[y1 * H + x1];
        float c0 = a + (bb - a) * wy;
        float c1 = cc + (d - cc) * wy;
        s[i][tid] = c0 + (c1 - c0) * wx - mean[lvl * 512 + b * 256 + c];
    }
    __syncthreads();
    union { unsigned short u[16]; bf16x8 v[2]; } h8, l8;
#pragma unroll
    for (int i = 0; i < 16; ++i) bf16split(s[i][tid], h8.u[i], l8.u[i]);
    size_t base = ((size_t)(img * 16 + ch) * 1024 + p) * 16;
    *(bf16x8*)&oh[base] = h8.v[0]; *(bf16x8*)&oh[base + 8] = h8.v[1];
    *(bf16x8*)&ol[base] = l8.v[0]; *(bf16x8*)&ol[base + 8] = l8.v[1];
}

// ---------------- merged direct MFMA 3x3 conv, XCD-swizzled 1D grid ----------------
__global__ __launch_bounds__(256) void conv3x3_all(
    const unsigned short* __restrict__ xT_h,  // [30][16][1024][16]
    const unsigned short* __restrict__ xT_l,
    const short* __restrict__ wp_hi_all,      // [6][9][160][256]
    const short* __restrict__ wp_lo_all,
    const float* __restrict__ biasc_all,      // [6][160]
    unsigned short* __restrict__ kt_hi, unsigned short* __restrict__ kt_lo,
    unsigned short* __restrict__ vt,
    unsigned short* __restrict__ kq_hi, unsigned short* __restrict__ kq_lo,
    unsigned short* __restrict__ vq)
{
    const int bid = blockIdx.x;
    const int xcd = bid & 7;
    const int j   = bid >> 3;        // 0..319
    const int grp = j % 5;
    const int k   = j / 5;           // 0..63
    const int yp  = k & 15;
    const int imgh = k >> 4;         // 0..3
    const int img = xcd + 8 * imgh;  // 0..31
    if (img >= 30) return;

    __shared__ float s_red[4][2][16][64];     // 32 KB
    const int tid = threadIdx.x;
    const bool iskey = (grp == 0);
    const int set = (img < 20) ? 0 : 1 + ((img - 20) >> 1);
    const int ocb = grp * 32;
    const int wave = tid >> 6, lane = tid & 63, l31 = tid & 31, lh = (tid >> 5) & 1;
    const int y0 = yp * 2;

    f32x16 acc0 = {}, acc1 = {};
    const bf16x8 bz = {};
    const unsigned short* xh = xT_h + (size_t)img * 16 * 16384;
    const unsigned short* xl = xT_l + (size_t)img * 16 * 16384;
    const short* wph = wp_hi_all + (size_t)set * 368640;
    const short* wpl = wp_lo_all + (size_t)set * 368640;
    const float* bset = biasc_all + set * 160;

    for (int cc = 0; cc < 4; ++cc) {
        const int ch = (wave << 2) + cc;
        const unsigned short* xhc = xh + (size_t)ch * 16384 + lh * 8;
        const unsigned short* xlc = xl + (size_t)ch * 16384 + lh * 8;
#pragma unroll
        for (int tg = 0; tg < 3; ++tg) {
            bf16x8 wh[3], wl[3];
#pragma unroll
            for (int tl = 0; tl < 3; ++tl) {
                size_t wi = ((size_t)((tg * 3 + tl) * 160 + ocb + l31)) * 256 + (ch << 4) + lh * 8;
                wh[tl] = *(const bf16x8*)&wph[wi];
                if (iskey) wl[tl] = *(const bf16x8*)&wpl[wi];
            }
#pragma unroll
            for (int nt = 0; nt < 2; ++nt) {
                const int ri = y0 + nt - 1 + tg;
                const bool rok = (ri >= 0 && ri < 32);
#pragma unroll
                for (int tl = 0; tl < 3; ++tl) {
                    const int x = l31 + tl - 1;
                    const bool ok = rok && (x >= 0) && (x < 32);
                    bf16x8 bh = bz, bl = bz;
                    if (ok) {
                        const int p = ri * 32 + x;
                        bh = *(const bf16x8*)&xhc[p * 16];
                        if (iskey) bl = *(const bf16x8*)&xlc[p * 16];
                    }
                    f32x16& a = nt ? acc1 : acc0;
                    a = __builtin_amdgcn_mfma_f32_32x32x16_bf16(wh[tl], bh, a, 0, 0, 0);
                    if (iskey) {
                        a = __builtin_amdgcn_mfma_f32_32x32x16_bf16(wh[tl], bl, a, 0, 0, 0);
                        a = __builtin_amdgcn_mfma_f32_32x32x16_bf16(wl[tl], bh, a, 0, 0, 0);
                    }
                }
            }
        }
    }
#pragma unroll
    for (int r = 0; r < 16; ++r) {
        s_red[wave][0][r][lane] = acc0[r];
        s_red[wave][1][r][lane] = acc1[r];
    }
    __syncthreads();
    float r0[4], r1[4];
#pragma unroll
    for (int jj = 0; jj < 4; ++jj) {
        int r = (wave << 2) + jj;
        r0[jj] = s_red[0][0][r][lane] + s_red[1][0][r][lane] + s_red[2][0][r][lane] + s_red[3][0][r][lane];
        r1[jj] = s_red[0][1][r][lane] + s_red[1][1][r][lane] + s_red[2][1][r][lane] + s_red[3][1][r][lane];
    }
    if (iskey) {
#pragma unroll
        for (int nt = 0; nt < 2; ++nt) {
            const float* rr = nt ? r1 : r0;
            int p = (y0 + nt) * 32 + l31;
            int ocq = 8 * wave + 4 * lh;
            us4 h4, l4;
#pragma unroll
            for (int jj = 0; jj < 4; ++jj) {
                unsigned short h, l;
                bf16split(rr[jj] + bset[ocq + jj], h, l);
                h4[jj] = h; l4[jj] = l;
            }
            if (img < 20) {
                size_t base = ((size_t)img * 1024 + p) * 32;
                *(us4*)&kt_hi[base + ocq] = h4;
                *(us4*)&kt_lo[base + ocq] = l4;
            } else {
                size_t base = ((size_t)(img - 20) * 1024 + p) * 32;
                *(us4*)&kq_hi[base + ocq] = h4;
                *(us4*)&kq_lo[base + ocq] = l4;
            }
        }
    } else {
#pragma unroll
        for (int nt = 0; nt < 2; ++nt) {
            const float* rr = nt ? r1 : r0;
            int p = (y0 + nt) * 32 + l31;
#pragma unroll
            for (int jj = 0; jj < 4; ++jj) {
                int pat = jj + 8 * wave + 4 * lh;
                int vo = (ocb - 32) + pat;
                unsigned short val = f2bf(rr[jj] + bset[32 + vo]);
                if (img < 20) vt[((size_t)img * 128 + vo) * 1024 + p] = val;
                else          vq[((size_t)(img - 20) * 128 + vo) * 1024 + p] = val;
            }
        }
    }
}

// ---------------- flash relation-attention v5b: 4-wave blocks, split-S + max tree ----------------
// grid (16 t-tiles of 64, 2 b, 40 = n*2+qg), block 256 = 4 waves: tw = w&1, vw = w>>1
__global__ __launch_bounds__(256, 2) void flash5(
    const unsigned short* __restrict__ kt_hi, const unsigned short* __restrict__ kt_lo,
    const unsigned short* __restrict__ vt_bf,
    const unsigned short* __restrict__ kq_hi, const unsigned short* __restrict__ kq_lo,
    const unsigned short* __restrict__ vq_bf,
    unsigned short* __restrict__ part2,      // [2 qg][20 n][2 b][256][1024] bf16
    float2* __restrict__ ml_out)             // [2 qg][20 n][2 b][1024] (m, l)
{
    const int tid = threadIdx.x;
    const int t0 = blockIdx.x * 64;
    const int b  = blockIdx.y;
    const int n  = blockIdx.z >> 1;
    const int qg = blockIdx.z & 1;
    const int qbase = qg * 512;
    const int wave = tid >> 6, lane = tid & 63, l31 = lane & 31, lh = lane >> 5;
    const int tw = wave & 1, vw = wave >> 1;

    const int trow = t0 + tw * 32 + l31;
    bf16x8 btk_h0, btk_h1, btk_l0, btk_l1;
    {
        size_t g = ((size_t)n * 1024 + trow) * 32 + lh * 8;
        btk_h0 = *(const bf16x8*)&kt_hi[g];
        btk_h1 = *(const bf16x8*)&kt_hi[g + 16];
        btk_l0 = *(const bf16x8*)&kt_lo[g];
        btk_l1 = *(const bf16x8*)&kt_lo[g + 16];
    }

    const unsigned short* vbase = (vw == 0)
        ? (vq_bf + (size_t)b * 131072)
        : (vt_bf + (size_t)n * 131072);
    const unsigned short* vrow[4];
#pragma unroll
    for (int vs = 0; vs < 4; ++vs)
        vrow[vs] = vbase + ((size_t)(vs * 32 + l31)) * 1024 + lh * 8;

    const unsigned short* kqh = kq_hi + (size_t)b * 1024 * 32;
    const unsigned short* kql = kq_lo + (size_t)b * 1024 * 32;

    bf16x8 nva[4][2];
#pragma unroll
    for (int vs = 0; vs < 4; ++vs) {
        nva[vs][0] = *(const bf16x8*)&vrow[vs][qbase];
        nva[vs][1] = *(const bf16x8*)&vrow[vs][qbase + 16];
    }
    bf16x8 nah0 = *(const bf16x8*)&kqh[(size_t)(qbase + l31) * 32 + lh * 8];
    bf16x8 nah1 = *(const bf16x8*)&kqh[(size_t)(qbase + l31) * 32 + 16 + lh * 8];
    bf16x8 nal0 = *(const bf16x8*)&kql[(size_t)(qbase + l31) * 32 + lh * 8];
    bf16x8 nal1 = *(const bf16x8*)&kql[(size_t)(qbase + l31) * 32 + 16 + lh * 8];

    f32x16 acc0 = {}, acc1 = {}, acc2 = {}, acc3 = {};
    float m = -3.0e38f, lsum = 0.f;

    for (int q0 = qbase; q0 < qbase + 512; q0 += 32) {
        bf16x8 va[4][2];
#pragma unroll
        for (int vs = 0; vs < 4; ++vs) { va[vs][0] = nva[vs][0]; va[vs][1] = nva[vs][1]; }
        bf16x8 ah0 = nah0, ah1 = nah1, al0 = nal0, al1 = nal1;

        if (q0 + 32 < qbase + 512) {   // issue next-step loads (overlap with compute)
            const int qn = q0 + 32;
#pragma unroll
            for (int vs = 0; vs < 4; ++vs) {
                nva[vs][0] = *(const bf16x8*)&vrow[vs][qn];
                nva[vs][1] = *(const bf16x8*)&vrow[vs][qn + 16];
            }
            size_t kb = (size_t)(qn + l31) * 32 + lh * 8;
            nah0 = *(const bf16x8*)&kqh[kb];
            nah1 = *(const bf16x8*)&kqh[kb + 16];
            nal0 = *(const bf16x8*)&kql[kb];
            nal1 = *(const bf16x8*)&kql[kb + 16];
        }

        // S tile in two INDEPENDENT MFMA chains (halves the serial dependency)
        f32x16 s1 = {}, s2 = {};
        __builtin_amdgcn_s_setprio(1);
        s1 = __builtin_amdgcn_mfma_f32_32x32x16_bf16(ah0, btk_h0, s1, 0, 0, 0);
        s2 = __builtin_amdgcn_mfma_f32_32x32x16_bf16(ah1, btk_h1, s2, 0, 0, 0);
        s1 = __builtin_amdgcn_mfma_f32_32x32x16_bf16(ah0, btk_l0, s1, 0, 0, 0);
        s2 = __builtin_amdgcn_mfma_f32_32x32x16_bf16(ah1, btk_l1, s2, 0, 0, 0);
        s1 = __builtin_amdgcn_mfma_f32_32x32x16_bf16(al0, btk_h0, s1, 0, 0, 0);
        s2 = __builtin_amdgcn_mfma_f32_32x32x16_bf16(al1, btk_h1, s2, 0, 0, 0);
        __builtin_amdgcn_s_setprio(0);
        f32x16 s = s1 + s2;

        // online softmax over q; pmax via depth-4 tree
        float t01 = fmaxf(s[0], s[1]),  t23 = fmaxf(s[2], s[3]);
        float t45 = fmaxf(s[4], s[5]),  t67 = fmaxf(s[6], s[7]);
        float t89 = fmaxf(s[8], s[9]),  tab = fmaxf(s[10], s[11]);
        float tcd = fmaxf(s[12], s[13]), tef = fmaxf(s[14], s[15]);
        float q0123 = fmaxf(t01, t23), q4567 = fmaxf(t45, t67);
        float q89ab = fmaxf(t89, tab), qcdef = fmaxf(tcd, tef);
        float pmax = fmaxf(fmaxf(q0123, q4567), fmaxf(q89ab, qcdef));
        pmax = fmaxf(pmax, __shfl_xor(pmax, 32));
        if (!__all(pmax <= m + 11.5417f)) {   // defer-max, THR = 8 nats in log2
            float mnew = fmaxf(m, pmax);
            float sc = __builtin_amdgcn_exp2f(m - mnew);
            m = mnew; lsum *= sc;
            acc0 *= sc; acc1 *= sc; acc2 *= sc; acc3 *= sc;
        }
        float pv[16]; float ps = 0.f;
#pragma unroll
        for (int r = 0; r < 16; ++r) { pv[r] = __builtin_amdgcn_exp2f(s[r] - m); ps += pv[r]; }
        lsum += ps;

        unsigned a0, a1, a2, a3, c0, c1, c2, c3;
        asm("v_cvt_pk_bf16_f32 %0, %1, %2" : "=v"(a0) : "v"(pv[0]),  "v"(pv[1]));
        asm("v_cvt_pk_bf16_f32 %0, %1, %2" : "=v"(a1) : "v"(pv[2]),  "v"(pv[3]));
        asm("v_cvt_pk_bf16_f32 %0, %1, %2" : "=v"(a2) : "v"(pv[4]),  "v"(pv[5]));
        asm("v_cvt_pk_bf16_f32 %0, %1, %2" : "=v"(a3) : "v"(pv[6]),  "v"(pv[7]));
        asm("v_cvt_pk_bf16_f32 %0, %1, %2" : "=v"(c0) : "v"(pv[8]),  "v"(pv[9]));
        asm("v_cvt_pk_bf16_f32 %0, %1, %2" : "=v"(c1) : "v"(pv[10]), "v"(pv[11]));
        asm("v_cvt_pk_bf16_f32 %0, %1, %2" : "=v"(c2) : "v"(pv[12]), "v"(pv[13]));
        asm("v_cvt_pk_bf16_f32 %0, %1, %2" : "=v"(c3) : "v"(pv[14]), "v"(pv[15]));
        asm("v_permlane32_swap_b32 %0, %1" : "+v"(a0), "+v"(a2));
        asm("v_permlane32_swap_b32 %0, %1" : "+v"(a1), "+v"(a3));
        asm("v_permlane32_swap_b32 %0, %1" : "+v"(c0), "+v"(c2));
        asm("v_permlane32_swap_b32 %0, %1" : "+v"(c1), "+v"(c3));
        union { unsigned u[4]; bf16x8 v; } f0, f1;
        f0.u[0] = a0; f0.u[1] = a1; f0.u[2] = a2; f0.u[3] = a3;
        f1.u[0] = c0; f1.u[1] = c1; f1.u[2] = c2; f1.u[3] = c3;

        __builtin_amdgcn_s_setprio(1);
#pragma unroll
        for (int vs = 0; vs < 4; ++vs) {
            f32x16& a = (vs == 0) ? acc0 : (vs == 1) ? acc1 : (vs == 2) ? acc2 : acc3;
            a = __builtin_amdgcn_mfma_f32_32x32x16_bf16(va[vs][0], f0.v, a, 0, 0, 0);
            a = __builtin_amdgcn_mfma_f32_32x32x16_bf16(va[vs][1], f1.v, a, 0, 0, 0);
        }
        __builtin_amdgcn_s_setprio(0);
    }

    float lt = lsum + __shfl_xor(lsum, 32);
    float linv = 1.f / lt;
    const size_t slab = (size_t)((qg * 20 + n) * 2 + b);
    unsigned short* outp = part2 + slab * 262144;
#pragma unroll
    for (int vs = 0; vs < 4; ++vs) {
        const f32x16& a = (vs == 0) ? acc0 : (vs == 1) ? acc1 : (vs == 2) ? acc2 : acc3;
#pragma unroll
        for (int r = 0; r < 16; ++r) {
            int v = vw * 128 + vs * 32 + (r & 3) + 8 * (r >> 2) + 4 * lh;
            outp[(size_t)v * 1024 + trow] = f2bf(a[r] * linv);
        }
    }
    if (vw == 0 && lh == 0)
        ml_out[slab * 1024 + trow] = make_float2(m, lt);
}

// ---------------- merge 2 q-groups x 20 n-slabs -> bf16 fsm slice ----------------
__global__ __launch_bounds__(256) void reduce40_merge(
    const unsigned short* __restrict__ part,  // [2][20][2][256][1024]
    const float2* __restrict__ ml,            // [2][20][2][1024]
    unsigned short* __restrict__ out)         // [2][256][1024]
{
    size_t i = (size_t)blockIdx.x * 256 + threadIdx.x;   // 0..524287
    const int t = (int)(i & 1023);
    const int b = (int)(i >> 18);
    const int vt_off = (int)(i & 262143);                 // v*1024 + t
    float s = 0.f;
#pragma unroll
    for (int n = 0; n < 20; ++n) {
        float2 ml0 = ml[(size_t)((0 * 20 + n) * 2 + b) * 1024 + t];
        float2 ml1 = ml[(size_t)((20 + n) * 2 + b) * 1024 + t];
        float M = fmaxf(ml0.x, ml1.x);
        float w0 = ml0.y * __builtin_amdgcn_exp2f(ml0.x - M);
        float w1 = ml1.y * __builtin_amdgcn_exp2f(ml1.x - M);
        float inv = 1.f / (w0 + w1);
        float v0 = bf2f(part[(size_t)((0 * 20 + n) * 2 + b) * 262144 + vt_off]);
        float v1 = bf2f(part[(size_t)((20 + n) * 2 + b) * 262144 + vt_off]);
        s += (v0 * w0 + v1 * w1) * inv;
    }
    out[i] = f2bf(s);
}

// ---------------- bilinear upsample fsm (bf16) -> finup (bf16), all levels, coalesced ----------------
__global__ __launch_bounds__(256) void upsample_all(
    const unsigned short* __restrict__ fsm, unsigned short* __restrict__ finup)
{
    static const size_t CUMF[5] = {0, 8388608, 10485760, 11010048, 11141120};
    const int lvl = blockIdx.y;
    const int lg = 7 - lvl, H = 128 >> lvl, HW = H * H;
    int idx = blockIdx.x * 256 + threadIdx.x;          // quad index
    if (idx >= (2 * 256 * HW) >> 2) return;
    const int p4 = (idx << 2) & (HW - 1);
    const int bc = (idx << 2) >> (2 * lg);             // 0..511 (b*256+c)
    const int y = p4 >> lg, x = p4 & (H - 1);
    const float sc = 31.f / (float)(H - 1);
    float fy = (float)y * sc;
    int y0 = (int)fy; int y1 = min(y0 + 1, 31); float wy = fy - (float)y0;
    const unsigned short* src = fsm + ((size_t)(lvl * 512 + bc)) * 1024;
    us4 o;
#pragma unroll
    for (int j = 0; j < 4; ++j) {
        float fx = (float)(x + j) * sc;
        int x0 = (int)fx; int x1 = min(x0 + 1, 31); float wx = fx - (float)x0;
        float a = bf2f(src[y0 * 32 + x0]), bb = bf2f(src[y1 * 32 + x0]);
        float cc = bf2f(src[y0 * 32 + x1]), d = bf2f(src[y1 * 32 + x1]);
        float c0 = a + (bb - a) * wy;
        float c1 = cc + (d - cc) * wy;
        o[j] = f2bf(c0 + (c1 - c0) * wx);
    }
    *(us4*)&finup[CUMF[lvl] + (size_t)bc * HW + p4] = o;
}

// ---------------- BN stats with fused bilinear upsample (32x32 -> HxH), all levels ----------------
__global__ __launch_bounds__(256) void bnstats2_all(
    const unsigned short* __restrict__ fsm, float* __restrict__ mu, float* __restrict__ var)
{
    const int c = blockIdx.x, lvl = blockIdx.y;
    const int lg = 7 - lvl, H = 128 >> lvl, HW = H * H;
    const float sc = 31.f / (float)(H - 1);
    float s = 0.f, s2 = 0.f;
    for (int u = threadIdx.x; u < 2 * HW; u += 256) {
        int b = (u >= HW) ? 1 : 0;
        int p = u - b * HW;
        int y = p >> lg, x = p & (H - 1);
        float fy = (float)y * sc, fx = (float)x * sc;
        int y0 = (int)fy, x0 = (int)fx;
        int y1 = min(y0 + 1, 31), x1 = min(x0 + 1, 31);
        float wy = fy - (float)y0, wx = fx - (float)x0;
        const unsigned short* src = fsm + ((size_t)(lvl * 2 + b) * 256 + c) * 1024;
        float a = bf2f(src[y0 * 32 + x0]), bb = bf2f(src[y1 * 32 + x0]);
        float cc = bf2f(src[y0 * 32 + x1]), d = bf2f(src[y1 * 32 + x1]);
        float c0 = a + (bb - a) * wy;
        float c1 = cc + (d - cc) * wy;
        float v = c0 + (c1 - c0) * wx;
        s += v; s2 += v * v;
    }
#pragma unroll
    for (int off = 32; off; off >>= 1) {
        s  += __shfl_xor(s, off);
        s2 += __shfl_xor(s2, off);
    }
    __shared__ float r1[4], r2[4];
    if ((threadIdx.x & 63) == 0) { r1[threadIdx.x >> 6] = s; r2[threadIdx.x >> 6] = s2; }
    __syncthreads();
    if (threadIdx.x == 0) {
        float cnt = 2.f * (float)HW;
        float mm = (r1[0] + r1[1] + r1[2] + r1[3]) / cnt;
        float qq = (r2[0] + r2[1] + r2[2] + r2[3]) / cnt;
        mu[lvl * 256 + c] = mm; var[lvl * 256 + c] = qq - mm * mm;
    }
}

// ---------------- fold BN into comb weights, all levels ----------------
__global__ __launch_bounds__(256) void prep_comb_all(
    const float* __restrict__ comb_w, const float* __restrict__ comb_b,
    const float* __restrict__ gamma, const float* __restrict__ beta,
    const float* __restrict__ mu, const float* __restrict__ var,
    short* __restrict__ wc, float* __restrict__ bias2)
{
    const int oc = blockIdx.x, lvl = blockIdx.y;
    const int ic = threadIdx.x;
    float a  = gamma[lvl * 256 + ic] * rsqrtf(var[lvl * 256 + ic] + 1e-5f);
    float bb = beta[lvl * 256 + ic] - mu[lvl * 256 + ic] * a;
    float w1 = comb_w[(size_t)oc * 512 + ic];
    float w2 = comb_w[(size_t)oc * 512 + 256 + ic];
    short* wcl = wc + (size_t)lvl * 131072;
    wcl[(size_t)oc * 512 + ic]       = (short)f2bf(w1);
    wcl[(size_t)oc * 512 + 256 + ic] = (short)f2bf(w2 * a);
    float s = w2 * bb;
#pragma unroll
    for (int off = 32; off; off >>= 1) s += __shfl_xor(s, off);
    __shared__ float red[4];
    if ((threadIdx.x & 63) == 0) red[threadIdx.x >> 6] = s;
    __syncthreads();
    if (threadIdx.x == 0)
        bias2[lvl * 256 + oc] = comb_b[oc] + red[0] + red[1] + red[2] + red[3];
}

// ---------------- comb 1x1 conv v2: 64-col tiles, finup bf16 X, all levels ----------------
// grid (341, 2): x<256 L0, <320 L1, <336 L2, <340 L3, else L4
__global__ __launch_bounds__(256, 1) void comb_all(
    const float* f0, const float* f1, const float* f2, const float* f3, const float* f4,
    const unsigned short* __restrict__ finup,  // packed per-level [2][256][HW] bf16
    const short* __restrict__ wc_all,          // [5][256][512] bf16
    const float* __restrict__ bias2_all,       // [5][256]
    float* __restrict__ out)
{
    __shared__ short s_wc[256 * 40];   // 20 KB
    __shared__ short s_xc[64 * 40];    // 5 KB
    static const size_t CUM[5] = {0, 8388608, 10485760, 11010048, 11141120};
    const int bx = blockIdx.x;
    int lvl, x0;
    if      (bx < 256) { lvl = 0; x0 = bx; }
    else if (bx < 320) { lvl = 1; x0 = bx - 256; }
    else if (bx < 336) { lvl = 2; x0 = bx - 320; }
    else if (bx < 340) { lvl = 3; x0 = bx - 336; }
    else               { lvl = 4; x0 = 0; }
    const int H = 128 >> lvl, HW = H * H;
    const float* f = sel5(f0, f1, f2, f3, f4, lvl);
    const unsigned short* fup = finup + CUM[lvl];
    const short* wc = wc_all + (size_t)lvl * 131072;
    const float* bias2 = bias2_all + lvl * 256;
    float* outl = out + CUM[lvl];

    const int tid = threadIdx.x;
    const int p0 = x0 * 64;
    const int b  = blockIdx.y;
    const int wv = tid >> 6, l31 = tid & 31, lh = (tid >> 5) & 1;

    f32x16 acc[2][2];
#pragma unroll
    for (int i = 0; i < 2; ++i)
#pragma unroll
        for (int j = 0; j < 2; ++j)
#pragma unroll
            for (int r = 0; r < 16; ++r) acc[i][j][r] = 0.f;

    for (int k0 = 0; k0 < 512; k0 += 32) {
        __syncthreads();
        for (int u = tid; u < 512; u += 256) {          // W: 256 rows x 32 k
            int r = u >> 1, h = u & 1;
            *(bf16x8*)&s_wc[r * 40 + h * 16 + 0] = *(const bf16x8*)&wc[(size_t)r * 512 + k0 + h * 16];
            *(bf16x8*)&s_wc[r * 40 + h * 16 + 8] = *(const bf16x8*)&wc[(size_t)r * 512 + k0 + h * 16 + 8];
        }
        for (int u = tid; u < 512; u += 256) {          // X: 32 k x 64 p -> [p][k]
            int kr = u >> 4, n4 = (u & 15) * 4;
            int ck = k0 + kr;
            int p = p0 + n4;
            if (ck < 256) {
                float4 v4 = *(const float4*)&f[((size_t)(b * 256 + ck)) * HW + p];
                s_xc[(n4 + 0) * 40 + kr] = (short)f2bf(v4.x);
                s_xc[(n4 + 1) * 40 + kr] = (short)f2bf(v4.y);
                s_xc[(n4 + 2) * 40 + kr] = (short)f2bf(v4.z);
                s_xc[(n4 + 3) * 40 + kr] = (short)f2bf(v4.w);
            } else {
                us4 v4 = *(const us4*)&fup[((size_t)(b * 256 + ck - 256)) * HW + p];
                s_xc[(n4 + 0) * 40 + kr] = (short)v4[0];
                s_xc[(n4 + 1) * 40 + kr] = (short)v4[1];
                s_xc[(n4 + 2) * 40 + kr] = (short)v4[2];
                s_xc[(n4 + 3) * 40 + kr] = (short)v4[3];
            }
        }
        __syncthreads();
#pragma unroll
        for (int ks = 0; ks < 2; ++ks) {
            bf16x8 a[2], bx2[2];
#pragma unroll
            for (int mi = 0; mi < 2; ++mi)
                a[mi] = *(const bf16x8*)&s_wc[(wv * 64 + mi * 32 + l31) * 40 + ks * 16 + lh * 8];
#pragma unroll
            for (int ni = 0; ni < 2; ++ni)
                bx2[ni] = *(const bf16x8*)&s_xc[(ni * 32 + l31) * 40 + ks * 16 + lh * 8];
#pragma unroll
            for (int mi = 0; mi < 2; ++mi)
#pragma unroll
                for (int ni = 0; ni < 2; ++ni)
                    acc[mi][ni] = __builtin_amdgcn_mfma_f32_32x32x16_bf16(a[mi], bx2[ni], acc[mi][ni], 0, 0, 0);
        }
    }
#pragma unroll
    for (int mi = 0; mi < 2; ++mi) {
#pragma unroll
        for (int ni = 0; ni < 2; ++ni) {
            int p = p0 + ni * 32 + l31;
#pragma unroll
            for (int r = 0; r < 16; ++r) {
                int oc = wv * 64 + mi * 32 + (r & 3) + 8 * (r >> 2) + 4 * lh;
                outl[((size_t)(b * 256 + oc)) * HW + p] = acc[mi][ni][r] + bias2[oc];
            }
        }
    }
}

// ---------------- host orchestration ----------------
extern "C" void kernel_launch(void* const* d_in, const int* in_sizes, int n_in,
                              void* d_out, int out_size, void* d_ws, size_t ws_size,
                              hipStream_t stream) {
    if (ws_size < WS_BYTES) return;

    const float* feats[5];
    for (int i = 0; i < 5; ++i) feats[i] = (const float*)d_in[i];
    const float* attn     = (const float*)d_in[5];
    const float* key_t_w  = (const float*)d_in[6];
    const float* key_t_b  = (const float*)d_in[7];
    const float* val_t_w  = (const float*)d_in[8];
    const float* val_t_b  = (const float*)d_in[9];
    const float* key_q_w  = (const float*)d_in[10];
    const float* key_q_b  = (const float*)d_in[11];
    const float* val_q_w  = (const float*)d_in[12];
    const float* val_q_b  = (const float*)d_in[13];
    const float* bn_gamma = (const float*)d_in[14];
    const float* bn_beta  = (const float*)d_in[15];
    const float* comb_w   = (const float*)d_in[16];
    const float* comb_b   = (const float*)d_in[17];

    char* ws = (char*)d_ws;
    float* biasc = (float*)(ws + B_BIASC);
    unsigned short* kt_hi = (unsigned short*)(ws + B_KTH);
    unsigned short* kt_lo = (unsigned short*)(ws + B_KTL);
    unsigned short* vt    = (unsigned short*)(ws + B_VT);
    unsigned short* kq_hi = (unsigned short*)(ws + B_KQH);
    unsigned short* kq_lo = (unsigned short*)(ws + B_KQL);
    unsigned short* vq    = (unsigned short*)(ws + B_VQ);
    float* mean_f = (float*)(ws + B_MEAN);
    unsigned short* fsm = (unsigned short*)(ws + B_FSM);
    float* mu     = (float*)(ws + B_MU);
    float* var    = (float*)(ws + B_VAR);
    short* wc_bf  = (short*)(ws + B_WC);
    float* bias2  = (float*)(ws + B_BIAS2);
    unsigned short* X_h = (unsigned short*)(ws + B_UNION + U_XH);
    unsigned short* X_l = (unsigned short*)(ws + B_UNION + U_XL);
    short* wp_hi = (short*)(ws + B_UNION + U_WPH);
    short* wp_lo = (short*)(ws + B_UNION + U_WPL);
    unsigned short* part2 = (unsigned short*)(ws + B_UNION + U_FPART);
    float2* ml_arr = (float2*)(ws + B_ML);
    unsigned short* finup = (unsigned short*)(ws + B_UNION);  // after part2 dead

    prep_weights<<<dim3(160, 6), 256, 0, stream>>>(
        key_t_w, key_t_b, val_t_w, val_t_b, key_q_w, key_q_b, val_q_w, val_q_b,
        wp_hi, wp_lo, biasc);

    transpose_split<<<dim3(20, 16, 4), 256, 0, stream>>>(attn, X_h, X_l);

    mean2d_all<<<dim3(512, 5), 256, 0, stream>>>(
        feats[0], feats[1], feats[2], feats[3], feats[4], mean_f);

    resizeT_all<<<dim3(2, 16, 20), 256, 0, stream>>>(
        feats[0], feats[1], feats[2], feats[3], feats[4], mean_f, X_h, X_l);

    conv3x3_all<<<2560, 256, 0, stream>>>(
        X_h, X_l, wp_hi, wp_lo, biasc, kt_hi, kt_lo, vt, kq_hi, kq_lo, vq);

    for (int idx = 0; idx < 5; ++idx) {
        flash5<<<dim3(16, 2, 40), 256, 0, stream>>>(
            kt_hi, kt_lo, vt,
            kq_hi + (size_t)idx * 2 * 32768,
            kq_lo + (size_t)idx * 2 * 32768,
            vq + (size_t)idx * 2 * 131072,
            part2, ml_arr);

        reduce40_merge<<<2048, 256, 0, stream>>>(part2, ml_arr, fsm + (size_t)idx * 524288);
    }

    upsample_all<<<dim3(8192, 5), 256, 0, stream>>>(fsm, finup);

    bnstats2_all<<<dim3(256, 5), 256, 0, stream>>>(fsm, mu, var);

    prep_comb_all<<<dim3(256, 5), 256, 0, stream>>>(
        comb_w, comb_b, bn_gamma, bn_beta, mu, var, wc_bf, bias2);

    comb_all<<<dim3(341, 2), 256, 0, stream>>>(
        feats[0], feats[1], feats[2], feats[3], feats[4],
        finup, wc_bf, bias2, (float*)d_out);
}

// Round 15
// 805.103 us; speedup vs baseline: 3.1823x; 1.0005x over previous
//
#include <hip/hip_runtime.h>
#include <cstddef>
#include <cstdint>

typedef __attribute__((ext_vector_type(8))) short bf16x8;
typedef __attribute__((ext_vector_type(16))) float f32x16;
typedef __attribute__((ext_vector_type(4))) unsigned short us4;

// ---------------- workspace layout (byte offsets) ----------------
static const size_t B_BIASC = 0;            // 6*160*4 = 3,840
static const size_t B_KTH   = 3840;         // 20*1024*32*2 = 1,310,720
static const size_t B_KTL   = 1314560;      // 1,310,720
static const size_t B_VT    = 2625280;      // 20*128*1024*2 = 5,242,880
static const size_t B_KQH   = 7868160;      // 5*2*1024*32*2 = 655,360
static const size_t B_KQL   = 8523520;      // 655,360
static const size_t B_VQ    = 9178880;      // 5*2*128*1024*2 = 2,621,440
static const size_t B_MEAN  = 11800320;     // 5*512*4 = 10,240
static const size_t B_FSM   = 11810560;     // 5*2*256*1024*2 = 5,242,880 (bf16)
static const size_t B_MU    = 17053440;     // 5*256*4 = 5,120
static const size_t B_VAR   = 17058560;     // 5,120
static const size_t B_WC    = 17063680;     // 5*256*512*2 = 1,310,720
static const size_t B_BIAS2 = 18374400;     // 5,120
static const size_t B_UNION = 18379520;     // 41,943,040 union region
// phase 1: X_all_hi +0 (15,728,640), X_all_lo +15,728,640, wp_hi +31,457,280, wp_lo +35,880,960
// phase 2 (per level): part2 +0 (41,943,040) -> reduce40 -> fsm
// phase 3: finup bf16 +0 (22,347,776) after part2 dead
static const size_t U_XH    = 0;
static const size_t U_XL    = 15728640;
static const size_t U_WPH   = 31457280;
static const size_t U_WPL   = 35880960;
static const size_t U_FPART = 0;
static const size_t B_ML    = 60322560;     // 2*20*2*1024*8 = 655,360 (float2 m,l)
static const size_t WS_BYTES = 60977920;    // ~61.0 MB

// ---------------- bf16 helpers (RNE) ----------------
__device__ inline unsigned short f2bf(float x) {
    unsigned u = __float_as_uint(x);
    return (unsigned short)((u + 0x7fffu + ((u >> 16) & 1u)) >> 16);
}
__device__ inline float bf2f(unsigned short u) {
    return __uint_as_float(((unsigned)u) << 16);
}
__device__ inline void bf16split(float x, unsigned short& hi, unsigned short& lo) {
    unsigned u = __float_as_uint(x);
    unsigned hb = (u + 0x7fffu + ((u >> 16) & 1u)) >> 16;
    hi = (unsigned short)hb;
    float hf = __uint_as_float(hb << 16);
    float r = x - hf;
    unsigned ur = __float_as_uint(r);
    lo = (unsigned short)((ur + 0x7fffu + ((ur >> 16) & 1u)) >> 16);
}
__device__ inline const float* sel5(const float* a, const float* b, const float* c,
                                    const float* d, const float* e, int i) {
    return i == 0 ? a : i == 1 ? b : i == 2 ? c : i == 3 ? d : e;
}

// ---------------- weight pre-transform ----------------
__global__ __launch_bounds__(256) void prep_weights(
    const float* __restrict__ kt_w, const float* __restrict__ kt_b,
    const float* __restrict__ vt_w, const float* __restrict__ vt_b,
    const float* __restrict__ kq_w, const float* __restrict__ kq_b,
    const float* __restrict__ vq_w, const float* __restrict__ vq_b,
    short* __restrict__ wp_hi, short* __restrict__ wp_lo, float* __restrict__ biasc)
{
    const int oc = blockIdx.x;    // 0..159
    const int s  = blockIdx.y;    // 0..5 (0 = stage A, 1+idx = level)
    const int ic = threadIdx.x;   // 0..255
    const bool iskey = oc < 32;
    const int ocl = iskey ? oc : oc - 32;
    const float scale = (iskey && s > 0) ? 1.4426950408889634f : 1.0f;
    const float* w = iskey
        ? (s == 0 ? kt_w : kq_w + (size_t)(s - 1) * 32 * 256 * 9)
        : (s == 0 ? vt_w : vq_w + (size_t)(s - 1) * 128 * 256 * 9);
    const float* wsrc = w + ((size_t)ocl * 256 + ic) * 9;
#pragma unroll
    for (int t = 0; t < 9; ++t) {
        unsigned short h, l; bf16split(wsrc[t] * scale, h, l);
        size_t d = ((size_t)(s * 9 + t) * 160 + oc) * 256 + ic;
        wp_hi[d] = (short)h; wp_lo[d] = (short)l;
    }
    if (ic == 0) {
        const float* bptr = iskey
            ? (s == 0 ? kt_b : kq_b + (s - 1) * 32)
            : (s == 0 ? vt_b : vq_b + (s - 1) * 128);
        biasc[s * 160 + oc] = bptr[ocl] * scale;
    }
}

// ---------------- fp32 [20][256][1024] -> bf16 hi/lo X_all imgs 0..19 ----------------
__global__ __launch_bounds__(256) void transpose_split(
    const float* __restrict__ in,
    unsigned short* __restrict__ oh, unsigned short* __restrict__ ol)
{
    __shared__ float s[16][260];
    const int n = blockIdx.x, ch = blockIdx.y, p0 = blockIdx.z * 256;
    const int tid = threadIdx.x;
#pragma unroll
    for (int i = 0; i < 16; ++i)
        s[i][tid] = in[((size_t)(n * 256 + ch * 16 + i)) * 1024 + p0 + tid];
    __syncthreads();
    union { unsigned short u[16]; bf16x8 v[2]; } h8, l8;
#pragma unroll
    for (int i = 0; i < 16; ++i) bf16split(s[i][tid], h8.u[i], l8.u[i]);
    size_t base = ((size_t)(n * 16 + ch) * 1024 + p0 + tid) * 16;
    *(bf16x8*)&oh[base] = h8.v[0]; *(bf16x8*)&oh[base + 8] = h8.v[1];
    *(bf16x8*)&ol[base] = l8.v[0]; *(bf16x8*)&ol[base + 8] = l8.v[1];
}

// ---------------- batched per (lvl,b,c) spatial mean ----------------
__global__ __launch_bounds__(256) void mean2d_all(
    const float* f0, const float* f1, const float* f2, const float* f3, const float* f4,
    float* __restrict__ mean)
{
    const int lvl = blockIdx.y;
    const float* f = sel5(f0, f1, f2, f3, f4, lvl);
    const int H = 128 >> lvl, HW = H * H;
    const int bc = blockIdx.x;
    const float* src = f + (size_t)bc * HW;
    float s = 0.f;
    for (int i = threadIdx.x; i < HW; i += 256) s += src[i];
#pragma unroll
    for (int off = 32; off; off >>= 1) s += __shfl_xor(s, off);
    __shared__ float red[4];
    if ((threadIdx.x & 63) == 0) red[threadIdx.x >> 6] = s;
    __syncthreads();
    if (threadIdx.x == 0)
        mean[lvl * 512 + bc] = (red[0] + red[1] + red[2] + red[3]) / (float)HW;
}

// ---------------- batched resize (HxH->32x32) + mean-sub -> X_all imgs 20..29 ----------------
__global__ __launch_bounds__(256) void resizeT_all(
    const float* f0, const float* f1, const float* f2, const float* f3, const float* f4,
    const float* __restrict__ mean,
    unsigned short* __restrict__ oh, unsigned short* __restrict__ ol)
{
    __shared__ float s[16][260];
    const int lvl = blockIdx.z >> 2;
    const int p0 = (blockIdx.z & 3) * 256;
    const int b = blockIdx.x, ch = blockIdx.y;
    const float* f = sel5(f0, f1, f2, f3, f4, lvl);
    const int H = 128 >> lvl;
    const int img = 20 + lvl * 2 + b;
    const int tid = threadIdx.x;
    const int p = p0 + tid, y = p >> 5, x = p & 31;
    float fy = (float)y * (float)(H - 1) / 31.0f;
    float fx = (float)x * (float)(H - 1) / 31.0f;
    int y0 = (int)fy; int y1 = min(y0 + 1, H - 1); float wy = fy - (float)y0;
    int x0 = (int)fx; int x1 = min(x0 + 1, H - 1); float wx = fx - (float)x0;
#pragma unroll
    for (int i = 0; i < 16; ++i) {
        int c = ch * 16 + i;
        const float* pf = f + ((size_t)(b * 256 + c)) * H * H;
        float a = pf[y0 * H + x0], bb = pf[y1 * H + x0];
        float cc = pf[y0 * H + x1], d = pf[y1 * H + x1];
        float c0 = a + (bb - a) * wy;
        float c1 = cc + (d - cc) * wy;
        s[i][tid] = c0 + (c1 - c0) * wx - mean[lvl * 512 + b * 256 + c];
    }
    __syncthreads();
    union { unsigned short u[16]; bf16x8 v[2]; } h8, l8;
#pragma unroll
    for (int i = 0; i < 16; ++i) bf16split(s[i][tid], h8.u[i], l8.u[i]);
    size_t base = ((size_t)(img * 16 + ch) * 1024 + p) * 16;
    *(bf16x8*)&oh[base] = h8.v[0]; *(bf16x8*)&oh[base + 8] = h8.v[1];
    *(bf16x8*)&ol[base] = l8.v[0]; *(bf16x8*)&ol[base + 8] = l8.v[1];
}

// ---------------- merged direct MFMA 3x3 conv, XCD-swizzled 1D grid ----------------
__global__ __launch_bounds__(256) void conv3x3_all(
    const unsigned short* __restrict__ xT_h,  // [30][16][1024][16]
    const unsigned short* __restrict__ xT_l,
    const short* __restrict__ wp_hi_all,      // [6][9][160][256]
    const short* __restrict__ wp_lo_all,
    const float* __restrict__ biasc_all,      // [6][160]
    unsigned short* __restrict__ kt_hi, unsigned short* __restrict__ kt_lo,
    unsigned short* __restrict__ vt,
    unsigned short* __restrict__ kq_hi, unsigned short* __restrict__ kq_lo,
    unsigned short* __restrict__ vq)
{
    const int bid = blockIdx.x;
    const int xcd = bid & 7;
    const int j   = bid >> 3;        // 0..319
    const int grp = j % 5;
    const int k   = j / 5;           // 0..63
    const int yp  = k & 15;
    const int imgh = k >> 4;         // 0..3
    const int img = xcd + 8 * imgh;  // 0..31
    if (img >= 30) return;

    __shared__ float s_red[4][2][16][64];     // 32 KB
    const int tid = threadIdx.x;
    const bool iskey = (grp == 0);
    const int set = (img < 20) ? 0 : 1 + ((img - 20) >> 1);
    const int ocb = grp * 32;
    const int wave = tid >> 6, lane = tid & 63, l31 = tid & 31, lh = (tid >> 5) & 1;
    const int y0 = yp * 2;

    f32x16 acc0 = {}, acc1 = {};
    const bf16x8 bz = {};
    const unsigned short* xh = xT_h + (size_t)img * 16 * 16384;
    const unsigned short* xl = xT_l + (size_t)img * 16 * 16384;
    const short* wph = wp_hi_all + (size_t)set * 368640;
    const short* wpl = wp_lo_all + (size_t)set * 368640;
    const float* bset = biasc_all + set * 160;

    for (int cc = 0; cc < 4; ++cc) {
        const int ch = (wave << 2) + cc;
        const unsigned short* xhc = xh + (size_t)ch * 16384 + lh * 8;
        const unsigned short* xlc = xl + (size_t)ch * 16384 + lh * 8;
#pragma unroll
        for (int tg = 0; tg < 3; ++tg) {
            bf16x8 wh[3], wl[3];
#pragma unroll
            for (int tl = 0; tl < 3; ++tl) {
                size_t wi = ((size_t)((tg * 3 + tl) * 160 + ocb + l31)) * 256 + (ch << 4) + lh * 8;
                wh[tl] = *(const bf16x8*)&wph[wi];
                if (iskey) wl[tl] = *(const bf16x8*)&wpl[wi];
            }
#pragma unroll
            for (int nt = 0; nt < 2; ++nt) {
                const int ri = y0 + nt - 1 + tg;
                const bool rok = (ri >= 0 && ri < 32);
#pragma unroll
                for (int tl = 0; tl < 3; ++tl) {
                    const int x = l31 + tl - 1;
                    const bool ok = rok && (x >= 0) && (x < 32);
                    bf16x8 bh = bz, bl = bz;
                    if (ok) {
                        const int p = ri * 32 + x;
                        bh = *(const bf16x8*)&xhc[p * 16];
                        if (iskey) bl = *(const bf16x8*)&xlc[p * 16];
                    }
                    f32x16& a = nt ? acc1 : acc0;
                    a = __builtin_amdgcn_mfma_f32_32x32x16_bf16(wh[tl], bh, a, 0, 0, 0);
                    if (iskey) {
                        a = __builtin_amdgcn_mfma_f32_32x32x16_bf16(wh[tl], bl, a, 0, 0, 0);
                        a = __builtin_amdgcn_mfma_f32_32x32x16_bf16(wl[tl], bh, a, 0, 0, 0);
                    }
                }
            }
        }
    }
#pragma unroll
    for (int r = 0; r < 16; ++r) {
        s_red[wave][0][r][lane] = acc0[r];
        s_red[wave][1][r][lane] = acc1[r];
    }
    __syncthreads();
    float r0[4], r1[4];
#pragma unroll
    for (int jj = 0; jj < 4; ++jj) {
        int r = (wave << 2) + jj;
        r0[jj] = s_red[0][0][r][lane] + s_red[1][0][r][lane] + s_red[2][0][r][lane] + s_red[3][0][r][lane];
        r1[jj] = s_red[0][1][r][lane] + s_red[1][1][r][lane] + s_red[2][1][r][lane] + s_red[3][1][r][lane];
    }
    if (iskey) {
#pragma unroll
        for (int nt = 0; nt < 2; ++nt) {
            const float* rr = nt ? r1 : r0;
            int p = (y0 + nt) * 32 + l31;
            int ocq = 8 * wave + 4 * lh;
            us4 h4, l4;
#pragma unroll
            for (int jj = 0; jj < 4; ++jj) {
                unsigned short h, l;
                bf16split(rr[jj] + bset[ocq + jj], h, l);
                h4[jj] = h; l4[jj] = l;
            }
            if (img < 20) {
                size_t base = ((size_t)img * 1024 + p) * 32;
                *(us4*)&kt_hi[base + ocq] = h4;
                *(us4*)&kt_lo[base + ocq] = l4;
            } else {
                size_t base = ((size_t)(img - 20) * 1024 + p) * 32;
                *(us4*)&kq_hi[base + ocq] = h4;
                *(us4*)&kq_lo[base + ocq] = l4;
            }
        }
    } else {
#pragma unroll
        for (int nt = 0; nt < 2; ++nt) {
            const float* rr = nt ? r1 : r0;
            int p = (y0 + nt) * 32 + l31;
#pragma unroll
            for (int jj = 0; jj < 4; ++jj) {
                int pat = jj + 8 * wave + 4 * lh;
                int vo = (ocb - 32) + pat;
                unsigned short val = f2bf(rr[jj] + bset[32 + vo]);
                if (img < 20) vt[((size_t)img * 128 + vo) * 1024 + p] = val;
                else          vq[((size_t)(img - 20) * 128 + vo) * 1024 + p] = val;
            }
        }
    }
}

// ---------------- flash relation-attention v7: in-place prefetch (no operand copies) ----------------
// grid (16 t-tiles of 64, 2 b, 40 = n*2+qg), block 256 = 4 waves: tw = w&1, vw = w>>1
// kq regs are reloaded right after the S-MFMAs consume them (softmax+PV covers latency);
// V regs reloaded right after PV consumes them (next step's S+softmax covers latency).
__global__ __launch_bounds__(256, 2) void flash7(
    const unsigned short* __restrict__ kt_hi, const unsigned short* __restrict__ kt_lo,
    const unsigned short* __restrict__ vt_bf,
    const unsigned short* __restrict__ kq_hi, const unsigned short* __restrict__ kq_lo,
    const unsigned short* __restrict__ vq_bf,
    unsigned short* __restrict__ part2,      // [2 qg][20 n][2 b][256][1024] bf16
    float2* __restrict__ ml_out)             // [2 qg][20 n][2 b][1024] (m, l)
{
    const int tid = threadIdx.x;
    const int t0 = blockIdx.x * 64;
    const int b  = blockIdx.y;
    const int n  = blockIdx.z >> 1;
    const int qg = blockIdx.z & 1;
    const int qbase = qg * 512;
    const int wave = tid >> 6, lane = tid & 63, l31 = lane & 31, lh = lane >> 5;
    const int tw = wave & 1, vw = wave >> 1;

    const int trow = t0 + tw * 32 + l31;
    bf16x8 btk_h0, btk_h1, btk_l0, btk_l1;
    {
        size_t g = ((size_t)n * 1024 + trow) * 32 + lh * 8;
        btk_h0 = *(const bf16x8*)&kt_hi[g];
        btk_h1 = *(const bf16x8*)&kt_hi[g + 16];
        btk_l0 = *(const bf16x8*)&kt_lo[g];
        btk_l1 = *(const bf16x8*)&kt_lo[g + 16];
    }

    const unsigned short* vbase = (vw == 0)
        ? (vq_bf + (size_t)b * 131072)
        : (vt_bf + (size_t)n * 131072);
    const unsigned short* vrow[4];
#pragma unroll
    for (int vs = 0; vs < 4; ++vs)
        vrow[vs] = vbase + ((size_t)(vs * 32 + l31)) * 1024 + lh * 8;

    const unsigned short* kqh = kq_hi + (size_t)b * 1024 * 32;
    const unsigned short* kql = kq_lo + (size_t)b * 1024 * 32;

    // initial operand load (step 0)
    bf16x8 vva[4][2];
#pragma unroll
    for (int vs = 0; vs < 4; ++vs) {
        vva[vs][0] = *(const bf16x8*)&vrow[vs][qbase];
        vva[vs][1] = *(const bf16x8*)&vrow[vs][qbase + 16];
    }
    bf16x8 ah0 = *(const bf16x8*)&kqh[(size_t)(qbase + l31) * 32 + lh * 8];
    bf16x8 ah1 = *(const bf16x8*)&kqh[(size_t)(qbase + l31) * 32 + 16 + lh * 8];
    bf16x8 al0 = *(const bf16x8*)&kql[(size_t)(qbase + l31) * 32 + lh * 8];
    bf16x8 al1 = *(const bf16x8*)&kql[(size_t)(qbase + l31) * 32 + 16 + lh * 8];

    f32x16 acc0 = {}, acc1 = {}, acc2 = {}, acc3 = {};
    float m = -3.0e38f, lsum = 0.f;

    for (int q0 = qbase; q0 < qbase + 512; q0 += 32) {
        const bool more = (q0 + 32 < qbase + 512);
        const int qn = q0 + 32;

        // S tile in two INDEPENDENT MFMA chains (consumes ah/al)
        f32x16 s1 = {}, s2 = {};
        __builtin_amdgcn_s_setprio(1);
        s1 = __builtin_amdgcn_mfma_f32_32x32x16_bf16(ah0, btk_h0, s1, 0, 0, 0);
        s2 = __builtin_amdgcn_mfma_f32_32x32x16_bf16(ah1, btk_h1, s2, 0, 0, 0);
        s1 = __builtin_amdgcn_mfma_f32_32x32x16_bf16(ah0, btk_l0, s1, 0, 0, 0);
        s2 = __builtin_amdgcn_mfma_f32_32x32x16_bf16(ah1, btk_l1, s2, 0, 0, 0);
        s1 = __builtin_amdgcn_mfma_f32_32x32x16_bf16(al0, btk_h0, s1, 0, 0, 0);
        s2 = __builtin_amdgcn_mfma_f32_32x32x16_bf16(al1, btk_h1, s2, 0, 0, 0);
        __builtin_amdgcn_s_setprio(0);

        // kq prefetch for next step, IN PLACE (ah/al dead after S issue);
        // softmax + PV below cover the L2 latency.
        if (more) {
            size_t kb = (size_t)(qn + l31) * 32 + lh * 8;
            ah0 = *(const bf16x8*)&kqh[kb];
            ah1 = *(const bf16x8*)&kqh[kb + 16];
            al0 = *(const bf16x8*)&kql[kb];
            al1 = *(const bf16x8*)&kql[kb + 16];
        }

        f32x16 s = s1 + s2;

        // online softmax over q; pmax via depth-4 tree
        float t01 = fmaxf(s[0], s[1]),  t23 = fmaxf(s[2], s[3]);
        float t45 = fmaxf(s[4], s[5]),  t67 = fmaxf(s[6], s[7]);
        float t89 = fmaxf(s[8], s[9]),  tab = fmaxf(s[10], s[11]);
        float tcd = fmaxf(s[12], s[13]), tef = fmaxf(s[14], s[15]);
        float q0123 = fmaxf(t01, t23), q4567 = fmaxf(t45, t67);
        float q89ab = fmaxf(t89, tab), qcdef = fmaxf(tcd, tef);
        float pmax = fmaxf(fmaxf(q0123, q4567), fmaxf(q89ab, qcdef));
        pmax = fmaxf(pmax, __shfl_xor(pmax, 32));
        if (!__all(pmax <= m + 11.5417f)) {   // defer-max, THR = 8 nats in log2
            float mnew = fmaxf(m, pmax);
            float sc = __builtin_amdgcn_exp2f(m - mnew);
            m = mnew; lsum *= sc;
            acc0 *= sc; acc1 *= sc; acc2 *= sc; acc3 *= sc;
        }
        float pv[16];
#pragma unroll
        for (int r = 0; r < 16; ++r) pv[r] = __builtin_amdgcn_exp2f(s[r] - m);
        // tree sum of pv
        {
            float a0s = pv[0] + pv[1],  a1s = pv[2] + pv[3];
            float a2s = pv[4] + pv[5],  a3s = pv[6] + pv[7];
            float a4s = pv[8] + pv[9],  a5s = pv[10] + pv[11];
            float a6s = pv[12] + pv[13], a7s = pv[14] + pv[15];
            float b0 = a0s + a1s, b1 = a2s + a3s, b2 = a4s + a5s, b3 = a6s + a7s;
            lsum += (b0 + b1) + (b2 + b3);
        }

        unsigned a0, a1, a2, a3, c0, c1, c2, c3;
        asm("v_cvt_pk_bf16_f32 %0, %1, %2" : "=v"(a0) : "v"(pv[0]),  "v"(pv[1]));
        asm("v_cvt_pk_bf16_f32 %0, %1, %2" : "=v"(a1) : "v"(pv[2]),  "v"(pv[3]));
        asm("v_cvt_pk_bf16_f32 %0, %1, %2" : "=v"(a2) : "v"(pv[4]),  "v"(pv[5]));
        asm("v_cvt_pk_bf16_f32 %0, %1, %2" : "=v"(a3) : "v"(pv[6]),  "v"(pv[7]));
        asm("v_cvt_pk_bf16_f32 %0, %1, %2" : "=v"(c0) : "v"(pv[8]),  "v"(pv[9]));
        asm("v_cvt_pk_bf16_f32 %0, %1, %2" : "=v"(c1) : "v"(pv[10]), "v"(pv[11]));
        asm("v_cvt_pk_bf16_f32 %0, %1, %2" : "=v"(c2) : "v"(pv[12]), "v"(pv[13]));
        asm("v_cvt_pk_bf16_f32 %0, %1, %2" : "=v"(c3) : "v"(pv[14]), "v"(pv[15]));
        asm("v_permlane32_swap_b32 %0, %1" : "+v"(a0), "+v"(a2));
        asm("v_permlane32_swap_b32 %0, %1" : "+v"(a1), "+v"(a3));
        asm("v_permlane32_swap_b32 %0, %1" : "+v"(c0), "+v"(c2));
        asm("v_permlane32_swap_b32 %0, %1" : "+v"(c1), "+v"(c3));
        union { unsigned u[4]; bf16x8 v; } f0, f1;
        f0.u[0] = a0; f0.u[1] = a1; f0.u[2] = a2; f0.u[3] = a3;
        f1.u[0] = c0; f1.u[1] = c1; f1.u[2] = c2; f1.u[3] = c3;

        // PV: consumes vva
        __builtin_amdgcn_s_setprio(1);
#pragma unroll
        for (int vs = 0; vs < 4; ++vs) {
            f32x16& a = (vs == 0) ? acc0 : (vs == 1) ? acc1 : (vs == 2) ? acc2 : acc3;
            a = __builtin_amdgcn_mfma_f32_32x32x16_bf16(vva[vs][0], f0.v, a, 0, 0, 0);
            a = __builtin_amdgcn_mfma_f32_32x32x16_bf16(vva[vs][1], f1.v, a, 0, 0, 0);
        }
        __builtin_amdgcn_s_setprio(0);

        // V prefetch for next step, IN PLACE (vva dead after PV issue);
        // next step's S+softmax covers the latency.
        if (more) {
#pragma unroll
            for (int vs = 0; vs < 4; ++vs) {
                vva[vs][0] = *(const bf16x8*)&vrow[vs][qn];
                vva[vs][1] = *(const bf16x8*)&vrow[vs][qn + 16];
            }
        }
    }

    float lt = lsum + __shfl_xor(lsum, 32);
    float linv = 1.f / lt;
    const size_t slab = (size_t)((qg * 20 + n) * 2 + b);
    unsigned short* outp = part2 + slab * 262144;
#pragma unroll
    for (int vs = 0; vs < 4; ++vs) {
        const f32x16& a = (vs == 0) ? acc0 : (vs == 1) ? acc1 : (vs == 2) ? acc2 : acc3;
#pragma unroll
        for (int r = 0; r < 16; ++r) {
            int v = vw * 128 + vs * 32 + (r & 3) + 8 * (r >> 2) + 4 * lh;
            outp[(size_t)v * 1024 + trow] = f2bf(a[r] * linv);
        }
    }
    if (vw == 0 && lh == 0)
        ml_out[slab * 1024 + trow] = make_float2(m, lt);
}

// ---------------- merge 2 q-groups x 20 n-slabs -> bf16 fsm slice ----------------
__global__ __launch_bounds__(256) void reduce40_merge(
    const unsigned short* __restrict__ part,  // [2][20][2][256][1024]
    const float2* __restrict__ ml,            // [2][20][2][1024]
    unsigned short* __restrict__ out)         // [2][256][1024]
{
    size_t i = (size_t)blockIdx.x * 256 + threadIdx.x;   // 0..524287
    const int t = (int)(i & 1023);
    const int b = (int)(i >> 18);
    const int vt_off = (int)(i & 262143);                 // v*1024 + t
    float s = 0.f;
#pragma unroll
    for (int n = 0; n < 20; ++n) {
        float2 ml0 = ml[(size_t)((0 * 20 + n) * 2 + b) * 1024 + t];
        float2 ml1 = ml[(size_t)((20 + n) * 2 + b) * 1024 + t];
        float M = fmaxf(ml0.x, ml1.x);
        float w0 = ml0.y * __builtin_amdgcn_exp2f(ml0.x - M);
        float w1 = ml1.y * __builtin_amdgcn_exp2f(ml1.x - M);
        float inv = 1.f / (w0 + w1);
        float v0 = bf2f(part[(size_t)((0 * 20 + n) * 2 + b) * 262144 + vt_off]);
        float v1 = bf2f(part[(size_t)((20 + n) * 2 + b) * 262144 + vt_off]);
        s += (v0 * w0 + v1 * w1) * inv;
    }
    out[i] = f2bf(s);
}

// ---------------- bilinear upsample fsm (bf16) -> finup (bf16), all levels, coalesced ----------------
__global__ __launch_bounds__(256) void upsample_all(
    const unsigned short* __restrict__ fsm, unsigned short* __restrict__ finup)
{
    static const size_t CUMF[5] = {0, 8388608, 10485760, 11010048, 11141120};
    const int lvl = blockIdx.y;
    const int lg = 7 - lvl, H = 128 >> lvl, HW = H * H;
    int idx = blockIdx.x * 256 + threadIdx.x;          // quad index
    if (idx >= (2 * 256 * HW) >> 2) return;
    const int p4 = (idx << 2) & (HW - 1);
    const int bc = (idx << 2) >> (2 * lg);             // 0..511 (b*256+c)
    const int y = p4 >> lg, x = p4 & (H - 1);
    const float sc = 31.f / (float)(H - 1);
    float fy = (float)y * sc;
    int y0 = (int)fy; int y1 = min(y0 + 1, 31); float wy = fy - (float)y0;
    const unsigned short* src = fsm + ((size_t)(lvl * 512 + bc)) * 1024;
    us4 o;
#pragma unroll
    for (int j = 0; j < 4; ++j) {
        float fx = (float)(x + j) * sc;
        int x0 = (int)fx; int x1 = min(x0 + 1, 31); float wx = fx - (float)x0;
        float a = bf2f(src[y0 * 32 + x0]), bb = bf2f(src[y1 * 32 + x0]);
        float cc = bf2f(src[y0 * 32 + x1]), d = bf2f(src[y1 * 32 + x1]);
        float c0 = a + (bb - a) * wy;
        float c1 = cc + (d - cc) * wy;
        o[j] = f2bf(c0 + (c1 - c0) * wx);
    }
    *(us4*)&finup[CUMF[lvl] + (size_t)bc * HW + p4] = o;
}

// ---------------- BN stats with fused bilinear upsample (32x32 -> HxH), all levels ----------------
__global__ __launch_bounds__(256) void bnstats2_all(
    const unsigned short* __restrict__ fsm, float* __restrict__ mu, float* __restrict__ var)
{
    const int c = blockIdx.x, lvl = blockIdx.y;
    const int lg = 7 - lvl, H = 128 >> lvl, HW = H * H;
    const float sc = 31.f / (float)(H - 1);
    float s = 0.f, s2 = 0.f;
    for (int u = threadIdx.x; u < 2 * HW; u += 256) {
        int b = (u >= HW) ? 1 : 0;
        int p = u - b * HW;
        int y = p >> lg, x = p & (H - 1);
        float fy = (float)y * sc, fx = (float)x * sc;
        int y0 = (int)fy, x0 = (int)fx;
        int y1 = min(y0 + 1, 31), x1 = min(x0 + 1, 31);
        float wy = fy - (float)y0, wx = fx - (float)x0;
        const unsigned short* src = fsm + ((size_t)(lvl * 2 + b) * 256 + c) * 1024;
        float a = bf2f(src[y0 * 32 + x0]), bb = bf2f(src[y1 * 32 + x0]);
        float cc = bf2f(src[y0 * 32 + x1]), d = bf2f(src[y1 * 32 + x1]);
        float c0 = a + (bb - a) * wy;
        float c1 = cc + (d - cc) * wy;
        float v = c0 + (c1 - c0) * wx;
        s += v; s2 += v * v;
    }
#pragma unroll
    for (int off = 32; off; off >>= 1) {
        s  += __shfl_xor(s, off);
        s2 += __shfl_xor(s2, off);
    }
    __shared__ float r1[4], r2[4];
    if ((threadIdx.x & 63) == 0) { r1[threadIdx.x >> 6] = s; r2[threadIdx.x >> 6] = s2; }
    __syncthreads();
    if (threadIdx.x == 0) {
        float cnt = 2.f * (float)HW;
        float mm = (r1[0] + r1[1] + r1[2] + r1[3]) / cnt;
        float qq = (r2[0] + r2[1] + r2[2] + r2[3]) / cnt;
        mu[lvl * 256 + c] = mm; var[lvl * 256 + c] = qq - mm * mm;
    }
}

// ---------------- fold BN into comb weights, all levels ----------------
__global__ __launch_bounds__(256) void prep_comb_all(
    const float* __restrict__ comb_w, const float* __restrict__ comb_b,
    const float* __restrict__ gamma, const float* __restrict__ beta,
    const float* __restrict__ mu, const float* __restrict__ var,
    short* __restrict__ wc, float* __restrict__ bias2)
{
    const int oc = blockIdx.x, lvl = blockIdx.y;
    const int ic = threadIdx.x;
    float a  = gamma[lvl * 256 + ic] * rsqrtf(var[lvl * 256 + ic] + 1e-5f);
    float bb = beta[lvl * 256 + ic] - mu[lvl * 256 + ic] * a;
    float w1 = comb_w[(size_t)oc * 512 + ic];
    float w2 = comb_w[(size_t)oc * 512 + 256 + ic];
    short* wcl = wc + (size_t)lvl * 131072;
    wcl[(size_t)oc * 512 + ic]       = (short)f2bf(w1);
    wcl[(size_t)oc * 512 + 256 + ic] = (short)f2bf(w2 * a);
    float s = w2 * bb;
#pragma unroll
    for (int off = 32; off; off >>= 1) s += __shfl_xor(s, off);
    __shared__ float red[4];
    if ((threadIdx.x & 63) == 0) red[threadIdx.x >> 6] = s;
    __syncthreads();
    if (threadIdx.x == 0)
        bias2[lvl * 256 + oc] = comb_b[oc] + red[0] + red[1] + red[2] + red[3];
}

// ---------------- comb 1x1 conv v2: 64-col tiles, finup bf16 X, all levels ----------------
// grid (341, 2): x<256 L0, <320 L1, <336 L2, <340 L3, else L4
__global__ __launch_bounds__(256, 1) void comb_all(
    const float* f0, const float* f1, const float* f2, const float* f3, const float* f4,
    const unsigned short* __restrict__ finup,  // packed per-level [2][256][HW] bf16
    const short* __restrict__ wc_all,          // [5][256][512] bf16
    const float* __restrict__ bias2_all,       // [5][256]
    float* __restrict__ out)
{
    __shared__ short s_wc[256 * 40];   // 20 KB
    __shared__ short s_xc[64 * 40];    // 5 KB
    static const size_t CUM[5] = {0, 8388608, 10485760, 11010048, 11141120};
    const int bx = blockIdx.x;
    int lvl, x0;
    if      (bx < 256) { lvl = 0; x0 = bx; }
    else if (bx < 320) { lvl = 1; x0 = bx - 256; }
    else if (bx < 336) { lvl = 2; x0 = bx - 320; }
    else if (bx < 340) { lvl = 3; x0 = bx - 336; }
    else               { lvl = 4; x0 = 0; }
    const int H = 128 >> lvl, HW = H * H;
    const float* f = sel5(f0, f1, f2, f3, f4, lvl);
    const unsigned short* fup = finup + CUM[lvl];
    const short* wc = wc_all + (size_t)lvl * 131072;
    const float* bias2 = bias2_all + lvl * 256;
    float* outl = out + CUM[lvl];

    const int tid = threadIdx.x;
    const int p0 = x0 * 64;
    const int b  = blockIdx.y;
    const int wv = tid >> 6, l31 = tid & 31, lh = (tid >> 5) & 1;

    f32x16 acc[2][2];
#pragma unroll
    for (int i = 0; i < 2; ++i)
#pragma unroll
        for (int j = 0; j < 2; ++j)
#pragma unroll
            for (int r = 0; r < 16; ++r) acc[i][j][r] = 0.f;

    for (int k0 = 0; k0 < 512; k0 += 32) {
        __syncthreads();
        for (int u = tid; u < 512; u += 256) {          // W: 256 rows x 32 k
            int r = u >> 1, h = u & 1;
            *(bf16x8*)&s_wc[r * 40 + h * 16 + 0] = *(const bf16x8*)&wc[(size_t)r * 512 + k0 + h * 16];
            *(bf16x8*)&s_wc[r * 40 + h * 16 + 8] = *(const bf16x8*)&wc[(size_t)r * 512 + k0 + h * 16 + 8];
        }
        for (int u = tid; u < 512; u += 256) {          // X: 32 k x 64 p -> [p][k]
            int kr = u >> 4, n4 = (u & 15) * 4;
            int ck = k0 + kr;
            int p = p0 + n4;
            if (ck < 256) {
                float4 v4 = *(const float4*)&f[((size_t)(b * 256 + ck)) * HW + p];
                s_xc[(n4 + 0) * 40 + kr] = (short)f2bf(v4.x);
                s_xc[(n4 + 1) * 40 + kr] = (short)f2bf(v4.y);
                s_xc[(n4 + 2) * 40 + kr] = (short)f2bf(v4.z);
                s_xc[(n4 + 3) * 40 + kr] = (short)f2bf(v4.w);
            } else {
                us4 v4 = *(const us4*)&fup[((size_t)(b * 256 + ck - 256)) * HW + p];
                s_xc[(n4 + 0) * 40 + kr] = (short)v4[0];
                s_xc[(n4 + 1) * 40 + kr] = (short)v4[1];
                s_xc[(n4 + 2) * 40 + kr] = (short)v4[2];
                s_xc[(n4 + 3) * 40 + kr] = (short)v4[3];
            }
        }
        __syncthreads();
#pragma unroll
        for (int ks = 0; ks < 2; ++ks) {
            bf16x8 a[2], bx2[2];
#pragma unroll
            for (int mi = 0; mi < 2; ++mi)
                a[mi] = *(const bf16x8*)&s_wc[(wv * 64 + mi * 32 + l31) * 40 + ks * 16 + lh * 8];
#pragma unroll
            for (int ni = 0; ni < 2; ++ni)
                bx2[ni] = *(const bf16x8*)&s_xc[(ni * 32 + l31) * 40 + ks * 16 + lh * 8];
#pragma unroll
            for (int mi = 0; mi < 2; ++mi)
#pragma unroll
                for (int ni = 0; ni < 2; ++ni)
                    acc[mi][ni] = __builtin_amdgcn_mfma_f32_32x32x16_bf16(a[mi], bx2[ni], acc[mi][ni], 0, 0, 0);
        }
    }
#pragma unroll
    for (int mi = 0; mi < 2; ++mi) {
#pragma unroll
        for (int ni = 0; ni < 2; ++ni) {
            int p = p0 + ni * 32 + l31;
#pragma unroll
            for (int r = 0; r < 16; ++r) {
                int oc = wv * 64 + mi * 32 + (r & 3) + 8 * (r >> 2) + 4 * lh;
                outl[((size_t)(b * 256 + oc)) * HW + p] = acc[mi][ni][r] + bias2[oc];
            }
        }
    }
}

// ---------------- host orchestration ----------------
extern "C" void kernel_launch(void* const* d_in, const int* in_sizes, int n_in,
                              void* d_out, int out_size, void* d_ws, size_t ws_size,
                              hipStream_t stream) {
    if (ws_size < WS_BYTES) return;

    const float* feats[5];
    for (int i = 0; i < 5; ++i) feats[i] = (const float*)d_in[i];
    const float* attn     = (const float*)d_in[5];
    const float* key_t_w  = (const float*)d_in[6];
    const float* key_t_b  = (const float*)d_in[7];
    const float* val_t_w  = (const float*)d_in[8];
    const float* val_t_b  = (const float*)d_in[9];
    const float* key_q_w  = (const float*)d_in[10];
    const float* key_q_b  = (const float*)d_in[11];
    const float* val_q_w  = (const float*)d_in[12];
    const float* val_q_b  = (const float*)d_in[13];
    const float* bn_gamma = (const float*)d_in[14];
    const float* bn_beta  = (const float*)d_in[15];
    const float* comb_w   = (const float*)d_in[16];
    const float* comb_b   = (const float*)d_in[17];

    char* ws = (char*)d_ws;
    float* biasc = (float*)(ws + B_BIASC);
    unsigned short* kt_hi = (unsigned short*)(ws + B_KTH);
    unsigned short* kt_lo = (unsigned short*)(ws + B_KTL);
    unsigned short* vt    = (unsigned short*)(ws + B_VT);
    unsigned short* kq_hi = (unsigned short*)(ws + B_KQH);
    unsigned short* kq_lo = (unsigned short*)(ws + B_KQL);
    unsigned short* vq    = (unsigned short*)(ws + B_VQ);
    float* mean_f = (float*)(ws + B_MEAN);
    unsigned short* fsm = (unsigned short*)(ws + B_FSM);
    float* mu     = (float*)(ws + B_MU);
    float* var    = (float*)(ws + B_VAR);
    short* wc_bf  = (short*)(ws + B_WC);
    float* bias2  = (float*)(ws + B_BIAS2);
    unsigned short* X_h = (unsigned short*)(ws + B_UNION + U_XH);
    unsigned short* X_l = (unsigned short*)(ws + B_UNION + U_XL);
    short* wp_hi = (short*)(ws + B_UNION + U_WPH);
    short* wp_lo = (short*)(ws + B_UNION + U_WPL);
    unsigned short* part2 = (unsigned short*)(ws + B_UNION + U_FPART);
    float2* ml_arr = (float2*)(ws + B_ML);
    unsigned short* finup = (unsigned short*)(ws + B_UNION);  // after part2 dead

    prep_weights<<<dim3(160, 6), 256, 0, stream>>>(
        key_t_w, key_t_b, val_t_w, val_t_b, key_q_w, key_q_b, val_q_w, val_q_b,
        wp_hi, wp_lo, biasc);

    transpose_split<<<dim3(20, 16, 4), 256, 0, stream>>>(attn, X_h, X_l);

    mean2d_all<<<dim3(512, 5), 256, 0, stream>>>(
        feats[0], feats[1], feats[2], feats[3], feats[4], mean_f);

    resizeT_all<<<dim3(2, 16, 20), 256, 0, stream>>>(
        feats[0], feats[1], feats[2], feats[3], feats[4], mean_f, X_h, X_l);

    conv3x3_all<<<2560, 256, 0, stream>>>(
        X_h, X_l, wp_hi, wp_lo, biasc, kt_hi, kt_lo, vt, kq_hi, kq_lo, vq);

    for (int idx = 0; idx < 5; ++idx) {
        flash7<<<dim3(16, 2, 40), 256, 0, stream>>>(
            kt_hi, kt_lo, vt,
            kq_hi + (size_t)idx * 2 * 32768,
            kq_lo + (size_t)idx * 2 * 32768,
            vq + (size_t)idx * 2 * 131072,
            part2, ml_arr);

        reduce40_merge<<<2048, 256, 0, stream>>>(part2, ml_arr, fsm + (size_t)idx * 524288);
    }

    upsample_all<<<dim3(8192, 5), 256, 0, stream>>>(fsm, finup);

    bnstats2_all<<<dim3(256, 5), 256, 0, stream>>>(fsm, mu, var);

    prep_comb_all<<<dim3(256, 5), 256, 0, stream>>>(
        comb_w, comb_b, bn_gamma, bn_beta, mu, var, wc_bf, bias2);

    comb_all<<<dim3(341, 2), 256, 0, stream>>>(
        feats[0], feats[1], feats[2], feats[3], feats[4],
        finup, wc_bf, bias2, (float*)d_out);
}